// Round 2
// baseline (652.111 us; speedup 1.0000x reference)
//
#include <hip/hip_runtime.h>
#include <hip/hip_bf16.h>

#define TT 2
#define HH 48
#define WW 48
#define CC 256
#define NHEADS 8
#define HDIM 32
#define SEQ 2048
#define NPIX (TT*HH*WW)   /* 4608 */
#define NPC  (NPIX*CC)    /* 1179648 */

// ---------------- Kernel 1: LayerNorm + QKV projection ----------------
// block = 256 threads (4 waves), 16 pixels per block; xn staged in LDS,
// each thread owns one output channel (row of W) for all 16 pixels.
__global__ __launch_bounds__(256) void k_ln_qkv(
    const float* __restrict__ x,
    const float* __restrict__ lnw, const float* __restrict__ lnb,
    const float* __restrict__ Wq, const float* __restrict__ Wk, const float* __restrict__ Wv,
    float* __restrict__ q, float* __restrict__ k, float* __restrict__ v)
{
    __shared__ float xn[16][CC];
    const int tid  = threadIdx.x;
    const int wv_  = tid >> 6;
    const int lane = tid & 63;
    const int p0   = blockIdx.x * 16;

    // Phase 1: LN. Each wave handles 4 pixels; lane covers 4 channels (float4).
    for (int pp = 0; pp < 4; ++pp) {
        const int pl = wv_ * 4 + pp;
        const int p  = p0 + pl;
        const float4 xv = *reinterpret_cast<const float4*>(x + (size_t)p * CC + lane * 4);
        float s  = xv.x + xv.y + xv.z + xv.w;
        float s2 = xv.x*xv.x + xv.y*xv.y + xv.z*xv.z + xv.w*xv.w;
        #pragma unroll
        for (int m = 1; m < 64; m <<= 1) {
            s  += __shfl_xor(s,  m, 64);
            s2 += __shfl_xor(s2, m, 64);
        }
        const float mu   = s * (1.0f / CC);
        const float var  = s2 * (1.0f / CC) - mu * mu;
        const float rstd = rsqrtf(var + 1e-6f);
        const float4 w4 = *reinterpret_cast<const float4*>(lnw + lane * 4);
        const float4 b4 = *reinterpret_cast<const float4*>(lnb + lane * 4);
        float4 o;
        o.x = (xv.x - mu) * rstd * w4.x + b4.x;
        o.y = (xv.y - mu) * rstd * w4.y + b4.y;
        o.z = (xv.z - mu) * rstd * w4.z + b4.z;
        o.w = (xv.w - mu) * rstd * w4.w + b4.w;
        *reinterpret_cast<float4*>(&xn[pl][lane * 4]) = o;
    }
    __syncthreads();

    // Phase 2: q/k/v[i] = sum_j xn[j] * W[i][j]  (W row-major, @ W.T)
    float aq[16], ak[16], av[16];
    #pragma unroll
    for (int p = 0; p < 16; ++p) { aq[p] = 0.f; ak[p] = 0.f; av[p] = 0.f; }
    const float* wqr = Wq + (size_t)tid * CC;
    const float* wkr = Wk + (size_t)tid * CC;
    const float* wvr = Wv + (size_t)tid * CC;
    for (int j = 0; j < CC; j += 4) {
        const float4 q4 = *reinterpret_cast<const float4*>(wqr + j);
        const float4 k4 = *reinterpret_cast<const float4*>(wkr + j);
        const float4 v4 = *reinterpret_cast<const float4*>(wvr + j);
        #pragma unroll
        for (int p = 0; p < 16; ++p) {
            const float4 xv = *reinterpret_cast<const float4*>(&xn[p][j]);
            aq[p] = fmaf(xv.x, q4.x, fmaf(xv.y, q4.y, fmaf(xv.z, q4.z, fmaf(xv.w, q4.w, aq[p]))));
            ak[p] = fmaf(xv.x, k4.x, fmaf(xv.y, k4.y, fmaf(xv.z, k4.z, fmaf(xv.w, k4.w, ak[p]))));
            av[p] = fmaf(xv.x, v4.x, fmaf(xv.y, v4.y, fmaf(xv.z, v4.z, fmaf(xv.w, v4.w, av[p]))));
        }
    }
    #pragma unroll
    for (int p = 0; p < 16; ++p) {
        const size_t o = (size_t)(p0 + p) * CC + tid;
        q[o] = aq[p]; k[o] = ak[p]; v[o] = av[p];
    }
}

// ---------------- Kernel 2: windowed flash attention (fp32) ----------------
// One thread owns one query row (q, acc, m, l in registers).
// Block = 256 threads = 256 query rows of one (window, head).
// K/V streamed through LDS in 32-key tiles; broadcast float4 reads.
__global__ __launch_bounds__(256) void k_attn(
    const float* __restrict__ q, const float* __restrict__ kk, const float* __restrict__ vv,
    float* __restrict__ O)
{
    __shared__ float Kt[32][HDIM];
    __shared__ float Vt[32][HDIM];
    const int bid  = blockIdx.x;
    const int rb   = bid & 7;          // query-row block within (win,head)
    const int head = (bid >> 3) & 7;
    const int win  = bid >> 6;         // 0..3
    const int rs = (win >> 1) * 16;
    const int cs = (win & 1) * 16;
    const int tid = threadIdx.x;

    const int srow = rb * 256 + tid;   // 0..2047 : s = tt*1024 + i*32 + j
    const int tt  = srow >> 10;
    const int rem = srow & 1023;
    const int yi  = rem >> 5;
    const int xj  = rem & 31;
    const size_t qbase = ((size_t)((tt * HH + rs + yi) * WW + cs + xj)) * CC + head * HDIM;

    const float scale = 0.17677669529663688f; // 32^-0.5, folded into q
    float4 qr[8];
    #pragma unroll
    for (int d = 0; d < 8; ++d) {
        float4 t = *reinterpret_cast<const float4*>(q + qbase + d * 4);
        t.x *= scale; t.y *= scale; t.z *= scale; t.w *= scale;
        qr[d] = t;
    }
    float4 acc[8];
    #pragma unroll
    for (int d = 0; d < 8; ++d) acc[d] = make_float4(0.f, 0.f, 0.f, 0.f);
    float mrun = -1e30f, lrun = 0.f;

    const int keyl = tid >> 3;        // 8 threads per key row
    const int d4   = (tid & 7) * 4;

    for (int kt0 = 0; kt0 < SEQ; kt0 += 32) {
        // cooperative K/V tile load (one float4 of K and V per thread)
        {
            const int skey = kt0 + keyl;
            const int ttk  = skey >> 10;
            const int remk = skey & 1023;
            const int yik  = remk >> 5;
            const int xjk  = remk & 31;
            const size_t kb = ((size_t)((ttk * HH + rs + yik) * WW + cs + xjk)) * CC
                              + head * HDIM + d4;
            *reinterpret_cast<float4*>(&Kt[keyl][d4]) = *reinterpret_cast<const float4*>(kk + kb);
            *reinterpret_cast<float4*>(&Vt[keyl][d4]) = *reinterpret_cast<const float4*>(vv + kb);
        }
        __syncthreads();

        float s[32];
        #pragma unroll
        for (int t2 = 0; t2 < 32; ++t2) {
            const float4* kr = reinterpret_cast<const float4*>(Kt[t2]);
            float d0 = 0.f;
            #pragma unroll
            for (int d = 0; d < 8; ++d) {
                const float4 kv = kr[d];
                d0 = fmaf(qr[d].x, kv.x, d0);
                d0 = fmaf(qr[d].y, kv.y, d0);
                d0 = fmaf(qr[d].z, kv.z, d0);
                d0 = fmaf(qr[d].w, kv.w, d0);
            }
            s[t2] = d0;
        }
        float tm = s[0];
        #pragma unroll
        for (int t2 = 1; t2 < 32; ++t2) tm = fmaxf(tm, s[t2]);
        const float mnew = fmaxf(mrun, tm);
        const float corr = __expf(mrun - mnew);
        lrun *= corr;
        #pragma unroll
        for (int d = 0; d < 8; ++d) {
            acc[d].x *= corr; acc[d].y *= corr; acc[d].z *= corr; acc[d].w *= corr;
        }
        #pragma unroll
        for (int t2 = 0; t2 < 32; ++t2) {
            const float p = __expf(s[t2] - mnew);
            lrun += p;
            const float4* vr = reinterpret_cast<const float4*>(Vt[t2]);
            #pragma unroll
            for (int d = 0; d < 8; ++d) {
                const float4 v4 = vr[d];
                acc[d].x = fmaf(p, v4.x, acc[d].x);
                acc[d].y = fmaf(p, v4.y, acc[d].y);
                acc[d].z = fmaf(p, v4.z, acc[d].z);
                acc[d].w = fmaf(p, v4.w, acc[d].w);
            }
        }
        mrun = mnew;
        __syncthreads();
    }
    const float inv = 1.0f / lrun;
    // O layout: [win][tt][i][j][head*32+d]
    const size_t ob = ((size_t)((win * TT + tt) * 1024 + yi * 32 + xj)) * CC + head * HDIM;
    #pragma unroll
    for (int d = 0; d < 8; ++d) {
        float4 t = acc[d];
        t.x *= inv; t.y *= inv; t.z *= inv; t.w *= inv;
        *reinterpret_cast<float4*>(O + ob + d * 4) = t;
    }
}

// ---------------- Kernel 3: overlap-add merge + output projection ----------------
__global__ __launch_bounds__(256) void k_merge_proj(
    const float* __restrict__ O, const float* __restrict__ Wo, const float* __restrict__ bo,
    float* __restrict__ out)
{
    __shared__ float md[16][CC];
    const int tid  = threadIdx.x;
    const int wv_  = tid >> 6;
    const int lane = tid & 63;
    const int p0   = blockIdx.x * 16;

    // Phase 1: gather merged = sum(windows)/count into LDS
    for (int pp = 0; pp < 4; ++pp) {
        const int pl = wv_ * 4 + pp;
        const int p  = p0 + pl;
        const int tt  = p / (HH * WW);
        const int rem = p % (HH * WW);
        const int y   = rem / WW;
        const int xc  = rem % WW;
        float4 a = make_float4(0.f, 0.f, 0.f, 0.f);
        int cnt = 0;
        for (int wr = 0; wr < 2; ++wr) {
            const int i = y - wr * 16;
            if (i < 0 || i >= 32) continue;
            for (int wc = 0; wc < 2; ++wc) {
                const int j = xc - wc * 16;
                if (j < 0 || j >= 32) continue;
                const int win = wr * 2 + wc;
                const size_t ob = ((size_t)((win * TT + tt) * 1024 + i * 32 + j)) * CC + lane * 4;
                const float4 t = *reinterpret_cast<const float4*>(O + ob);
                a.x += t.x; a.y += t.y; a.z += t.z; a.w += t.w;
                ++cnt;
            }
        }
        const float ic = 1.0f / (float)cnt;
        a.x *= ic; a.y *= ic; a.z *= ic; a.w *= ic;
        *reinterpret_cast<float4*>(&md[pl][lane * 4]) = a;
    }
    __syncthreads();

    // Phase 2: out[i] = merged . Wo[i][:] + bo[i], store fp32
    float a[16];
    #pragma unroll
    for (int p = 0; p < 16; ++p) a[p] = 0.f;
    const float* wor = Wo + (size_t)tid * CC;
    for (int j = 0; j < CC; j += 4) {
        const float4 w4 = *reinterpret_cast<const float4*>(wor + j);
        #pragma unroll
        for (int p = 0; p < 16; ++p) {
            const float4 mv = *reinterpret_cast<const float4*>(&md[p][j]);
            a[p] = fmaf(mv.x, w4.x, fmaf(mv.y, w4.y, fmaf(mv.z, w4.z, fmaf(mv.w, w4.w, a[p]))));
        }
    }
    const float bias = bo[tid];
    #pragma unroll
    for (int p = 0; p < 16; ++p) {
        out[(size_t)(p0 + p) * CC + tid] = a[p] + bias;
    }
}

extern "C" void kernel_launch(void* const* d_in, const int* in_sizes, int n_in,
                              void* d_out, int out_size, void* d_ws, size_t ws_size,
                              hipStream_t stream)
{
    const float* x   = (const float*)d_in[0];
    const float* lnw = (const float*)d_in[1];
    const float* lnb = (const float*)d_in[2];
    const float* Wq  = (const float*)d_in[3];
    const float* Wk  = (const float*)d_in[4];
    const float* Wv  = (const float*)d_in[5];
    const float* Wo  = (const float*)d_in[6];
    const float* bo  = (const float*)d_in[7];

    float* ws = (float*)d_ws;
    float* q = ws;              // 1179648 floats
    float* k = q + NPC;         // 1179648
    float* v = k + NPC;         // 1179648
    float* O = v + NPC;         // 4*2048*256 = 2097152 floats

    k_ln_qkv<<<NPIX / 16, 256, 0, stream>>>(x, lnw, lnb, Wq, Wk, Wv, q, k, v);
    k_attn<<<256, 256, 0, stream>>>(q, k, v, O);
    k_merge_proj<<<NPIX / 16, 256, 0, stream>>>(O, Wo, bo, (float*)d_out);
}

// Round 3
// 206.709 us; speedup vs baseline: 3.1547x; 3.1547x over previous
//
#include <hip/hip_runtime.h>
#include <hip/hip_bf16.h>

#define TT 2
#define HH 48
#define WW 48
#define CC 256
#define NHEADS 8
#define HDIM 32
#define SEQ 2048
#define NPIX (TT*HH*WW)   /* 4608 */
#define NPC  (NPIX*CC)    /* 1179648 */

typedef __attribute__((ext_vector_type(8))) short bf16x8;
typedef __attribute__((ext_vector_type(4))) float f32x4;

__device__ inline unsigned cvt_pk_bf16(float lo, float hi) {
    unsigned r;
    asm("v_cvt_pk_bf16_f32 %0, %1, %2" : "=v"(r) : "v"(lo), "v"(hi));
    return r;
}

// ---------------- Kernel 1: LayerNorm + QKV projection (bf16 out) ----------------
// Q pre-scaled by hd^-0.5 * log2(e) so attention scores are log2-domain.
// V written TRANSPOSED ([channel][pixel]) so attention's V^T MFMA A-frags are
// contiguous 16B loads.
__global__ __launch_bounds__(256) void k_ln_qkv(
    const float* __restrict__ x,
    const float* __restrict__ lnw, const float* __restrict__ lnb,
    const float* __restrict__ Wq, const float* __restrict__ Wk, const float* __restrict__ Wv,
    __hip_bfloat16* __restrict__ qb, __hip_bfloat16* __restrict__ kb,
    __hip_bfloat16* __restrict__ vtb)
{
    __shared__ float xn[16][CC];
    const int tid  = threadIdx.x;
    const int wv_  = tid >> 6;
    const int lane = tid & 63;
    const int p0   = blockIdx.x * 16;

    for (int pp = 0; pp < 4; ++pp) {
        const int pl = wv_ * 4 + pp;
        const int p  = p0 + pl;
        const float4 xv = *reinterpret_cast<const float4*>(x + (size_t)p * CC + lane * 4);
        float s  = xv.x + xv.y + xv.z + xv.w;
        float s2 = xv.x*xv.x + xv.y*xv.y + xv.z*xv.z + xv.w*xv.w;
        #pragma unroll
        for (int m = 1; m < 64; m <<= 1) {
            s  += __shfl_xor(s,  m, 64);
            s2 += __shfl_xor(s2, m, 64);
        }
        const float mu   = s * (1.0f / CC);
        const float var  = s2 * (1.0f / CC) - mu * mu;
        const float rstd = rsqrtf(var + 1e-6f);
        const float4 w4 = *reinterpret_cast<const float4*>(lnw + lane * 4);
        const float4 b4 = *reinterpret_cast<const float4*>(lnb + lane * 4);
        float4 o;
        o.x = (xv.x - mu) * rstd * w4.x + b4.x;
        o.y = (xv.y - mu) * rstd * w4.y + b4.y;
        o.z = (xv.z - mu) * rstd * w4.z + b4.z;
        o.w = (xv.w - mu) * rstd * w4.w + b4.w;
        *reinterpret_cast<float4*>(&xn[pl][lane * 4]) = o;
    }
    __syncthreads();

    float aq[16], ak[16], av[16];
    #pragma unroll
    for (int p = 0; p < 16; ++p) { aq[p] = 0.f; ak[p] = 0.f; av[p] = 0.f; }
    const float* wqr = Wq + (size_t)tid * CC;
    const float* wkr = Wk + (size_t)tid * CC;
    const float* wvr = Wv + (size_t)tid * CC;
    for (int j = 0; j < CC; j += 4) {
        const float4 q4 = *reinterpret_cast<const float4*>(wqr + j);
        const float4 k4 = *reinterpret_cast<const float4*>(wkr + j);
        const float4 v4 = *reinterpret_cast<const float4*>(wvr + j);
        #pragma unroll
        for (int p = 0; p < 16; ++p) {
            const float4 xv = *reinterpret_cast<const float4*>(&xn[p][j]);
            aq[p] = fmaf(xv.x, q4.x, fmaf(xv.y, q4.y, fmaf(xv.z, q4.z, fmaf(xv.w, q4.w, aq[p]))));
            ak[p] = fmaf(xv.x, k4.x, fmaf(xv.y, k4.y, fmaf(xv.z, k4.z, fmaf(xv.w, k4.w, ak[p]))));
            av[p] = fmaf(xv.x, v4.x, fmaf(xv.y, v4.y, fmaf(xv.z, v4.z, fmaf(xv.w, v4.w, av[p]))));
        }
    }
    const float QSC = 0.17677669529663688f * 1.4426950408889634f;
    __hip_bfloat16 vloc[16];
    #pragma unroll
    for (int p = 0; p < 16; ++p) {
        const size_t o = (size_t)(p0 + p) * CC + tid;
        qb[o] = __float2bfloat16(aq[p] * QSC);
        kb[o] = __float2bfloat16(ak[p]);
        vloc[p] = __float2bfloat16(av[p]);
    }
    uint4* vdst = reinterpret_cast<uint4*>(vtb + (size_t)tid * NPIX + p0);
    const uint4* vsrc = reinterpret_cast<const uint4*>(vloc);
    vdst[0] = vsrc[0];
    vdst[1] = vsrc[1];
}

// ---------------- Kernel 2: MFMA flash attention ----------------
// One wave per block; wave owns 32 q-rows of one (win, head).
// Swapped QK^T: scores C[key][q] (q = lane&15) -> lane-local softmax.
// P redistributed to B-frag layout via cvt_pk_bf16 + ds_bpermute.
// PV computed as out^T = mfma(V^T, P). No LDS tiles, no barriers.
__global__ __launch_bounds__(64) void k_attn_mfma(
    const __hip_bfloat16* __restrict__ qbp, const __hip_bfloat16* __restrict__ kbp,
    const __hip_bfloat16* __restrict__ vtb, float* __restrict__ O)
{
    const int lane = threadIdx.x;
    const int bid  = blockIdx.x;
    const int qblk = bid & 63;
    const int head = (bid >> 6) & 7;
    const int win  = bid >> 9;
    const int rs = (win >> 1) * 16, cs = (win & 1) * 16;
    const int g = lane >> 4, q16 = lane & 15;

    // Q fragments (B-operand layout): lane holds Q[q=lane&15][hd=g*8+j]
    bf16x8 qf[2];
    int qpix[2];
    #pragma unroll
    for (int qt = 0; qt < 2; ++qt) {
        const int s = qblk * 32 + qt * 16 + q16;
        const int tt = s >> 10, yi = (s >> 5) & 31, xj = s & 31;
        qpix[qt] = (tt * HH + rs + yi) * WW + cs + xj;
        qf[qt] = *reinterpret_cast<const bf16x8*>(
            qbp + (size_t)qpix[qt] * CC + head * HDIM + g * 8);
    }

    f32x4 acc[2][2]; // [dt][qt]
    #pragma unroll
    for (int a = 0; a < 2; ++a)
        #pragma unroll
        for (int b = 0; b < 2; ++b) acc[a][b] = (f32x4){0.f, 0.f, 0.f, 0.f};
    float mrun[2] = {-3e38f, -3e38f};
    float lrun[2] = {0.f, 0.f};

    const __hip_bfloat16* vrow0 = vtb + (size_t)(head * HDIM + q16) * NPIX;
    const __hip_bfloat16* vrow1 = vrow0 + (size_t)16 * NPIX;

    const int idxA = ((2 * (g & 1)) * 16 + q16) * 4; // src lane*4 for key pairs j=0..3
    const int idxB = idxA + 64;                      // +1 group for j=4..7

    for (int kv0 = 0; kv0 < SEQ; kv0 += 32) {
        // K fragments (A-operand): lane holds K[key=kt*16+q16][hd=g*8+j]
        bf16x8 kf0, kf1;
        {
            int sk = kv0 + q16;
            int tt = sk >> 10, yi = (sk >> 5) & 31, xj = sk & 31;
            int kpix = (tt * HH + rs + yi) * WW + cs + xj;
            kf0 = *reinterpret_cast<const bf16x8*>(kbp + (size_t)kpix * CC + head * HDIM + g * 8);
            sk = kv0 + 16 + q16;
            tt = sk >> 10; yi = (sk >> 5) & 31; xj = sk & 31;
            kpix = (tt * HH + rs + yi) * WW + cs + xj;
            kf1 = *reinterpret_cast<const bf16x8*>(kbp + (size_t)kpix * CC + head * HDIM + g * 8);
        }
        // V^T fragments (A-operand): lane holds V[key=kv0+g*8+j][d=dt*16+q16]
        bf16x8 vf0, vf1;
        {
            const int sk = kv0 + g * 8;
            const int tt = sk >> 10, yi = (sk >> 5) & 31, xj = sk & 31;
            const int vpix = (tt * HH + rs + yi) * WW + cs + xj;
            vf0 = *reinterpret_cast<const bf16x8*>(vrow0 + vpix);
            vf1 = *reinterpret_cast<const bf16x8*>(vrow1 + vpix);
        }
        #pragma unroll
        for (int qt = 0; qt < 2; ++qt) {
            const f32x4 z = {0.f, 0.f, 0.f, 0.f};
            f32x4 s0 = __builtin_amdgcn_mfma_f32_16x16x32_bf16(kf0, qf[qt], z, 0, 0, 0);
            f32x4 s1 = __builtin_amdgcn_mfma_f32_16x16x32_bf16(kf1, qf[qt], z, 0, 0, 0);
            // scores are log2-domain (scale folded into Q)
            float tm = fmaxf(fmaxf(fmaxf(s0[0], s0[1]), fmaxf(s0[2], s0[3])),
                             fmaxf(fmaxf(s1[0], s1[1]), fmaxf(s1[2], s1[3])));
            tm = fmaxf(tm, __shfl_xor(tm, 16, 64));
            tm = fmaxf(tm, __shfl_xor(tm, 32, 64));
            const float mnew = fmaxf(mrun[qt], tm);
            const float corr = exp2f(mrun[qt] - mnew);
            const float p00 = exp2f(s0[0] - mnew), p01 = exp2f(s0[1] - mnew);
            const float p02 = exp2f(s0[2] - mnew), p03 = exp2f(s0[3] - mnew);
            const float p10 = exp2f(s1[0] - mnew), p11 = exp2f(s1[1] - mnew);
            const float p12 = exp2f(s1[2] - mnew), p13 = exp2f(s1[3] - mnew);
            float ts = ((p00 + p01) + (p02 + p03)) + ((p10 + p11) + (p12 + p13));
            ts += __shfl_xor(ts, 16, 64);
            ts += __shfl_xor(ts, 32, 64);
            lrun[qt] = lrun[qt] * corr + ts;
            acc[0][qt] *= corr;
            acc[1][qt] *= corr;
            mrun[qt] = mnew;
            // pack P to bf16 pairs, redistribute to B-frag layout
            const unsigned pk00 = cvt_pk_bf16(p00, p01); // kt2=0, keys (gs*4+0, +1)
            const unsigned pk01 = cvt_pk_bf16(p02, p03); // kt2=0, keys (gs*4+2, +3)
            const unsigned pk10 = cvt_pk_bf16(p10, p11); // kt2=1
            const unsigned pk11 = cvt_pk_bf16(p12, p13);
            union { int i[4]; bf16x8 v; } pf;
            {
                int a0 = __builtin_amdgcn_ds_bpermute(idxA, (int)pk00);
                int a1 = __builtin_amdgcn_ds_bpermute(idxA, (int)pk10);
                pf.i[0] = (g < 2) ? a0 : a1;
                a0 = __builtin_amdgcn_ds_bpermute(idxA, (int)pk01);
                a1 = __builtin_amdgcn_ds_bpermute(idxA, (int)pk11);
                pf.i[1] = (g < 2) ? a0 : a1;
                a0 = __builtin_amdgcn_ds_bpermute(idxB, (int)pk00);
                a1 = __builtin_amdgcn_ds_bpermute(idxB, (int)pk10);
                pf.i[2] = (g < 2) ? a0 : a1;
                a0 = __builtin_amdgcn_ds_bpermute(idxB, (int)pk01);
                a1 = __builtin_amdgcn_ds_bpermute(idxB, (int)pk11);
                pf.i[3] = (g < 2) ? a0 : a1;
            }
            acc[0][qt] = __builtin_amdgcn_mfma_f32_16x16x32_bf16(vf0, pf.v, acc[0][qt], 0, 0, 0);
            acc[1][qt] = __builtin_amdgcn_mfma_f32_16x16x32_bf16(vf1, pf.v, acc[1][qt], 0, 0, 0);
        }
    }

    // Epilogue: out[q][d] = acc^T / l ; C row = d_local = g*4+reg (consecutive -> float4)
    #pragma unroll
    for (int qt = 0; qt < 2; ++qt) {
        const float inv = 1.0f / lrun[qt];
        const int s = qblk * 32 + qt * 16 + q16;
        const int tt = s >> 10, yi = (s >> 5) & 31, xj = s & 31;
        const size_t opix = (size_t)(win * TT + tt) * 1024 + yi * 32 + xj;
        #pragma unroll
        for (int dt = 0; dt < 2; ++dt) {
            f32x4 o = acc[dt][qt];
            o *= inv;
            *reinterpret_cast<f32x4*>(O + opix * CC + head * HDIM + dt * 16 + g * 4) = o;
        }
    }
}

// ---------------- Kernel 3: overlap-add merge + output projection ----------------
__global__ __launch_bounds__(256) void k_merge_proj(
    const float* __restrict__ O, const float* __restrict__ Wo, const float* __restrict__ bo,
    float* __restrict__ out)
{
    __shared__ float md[16][CC];
    const int tid  = threadIdx.x;
    const int wv_  = tid >> 6;
    const int lane = tid & 63;
    const int p0   = blockIdx.x * 16;

    for (int pp = 0; pp < 4; ++pp) {
        const int pl = wv_ * 4 + pp;
        const int p  = p0 + pl;
        const int tt  = p / (HH * WW);
        const int rem = p % (HH * WW);
        const int y   = rem / WW;
        const int xc  = rem % WW;
        float4 a = make_float4(0.f, 0.f, 0.f, 0.f);
        int cnt = 0;
        for (int wr = 0; wr < 2; ++wr) {
            const int i = y - wr * 16;
            if (i < 0 || i >= 32) continue;
            for (int wc = 0; wc < 2; ++wc) {
                const int j = xc - wc * 16;
                if (j < 0 || j >= 32) continue;
                const int win = wr * 2 + wc;
                const size_t ob = ((size_t)((win * TT + tt) * 1024 + i * 32 + j)) * CC + lane * 4;
                const float4 t = *reinterpret_cast<const float4*>(O + ob);
                a.x += t.x; a.y += t.y; a.z += t.z; a.w += t.w;
                ++cnt;
            }
        }
        const float ic = 1.0f / (float)cnt;
        a.x *= ic; a.y *= ic; a.z *= ic; a.w *= ic;
        *reinterpret_cast<float4*>(&md[pl][lane * 4]) = a;
    }
    __syncthreads();

    float a[16];
    #pragma unroll
    for (int p = 0; p < 16; ++p) a[p] = 0.f;
    const float* wor = Wo + (size_t)tid * CC;
    for (int j = 0; j < CC; j += 4) {
        const float4 w4 = *reinterpret_cast<const float4*>(wor + j);
        #pragma unroll
        for (int p = 0; p < 16; ++p) {
            const float4 mv = *reinterpret_cast<const float4*>(&md[p][j]);
            a[p] = fmaf(mv.x, w4.x, fmaf(mv.y, w4.y, fmaf(mv.z, w4.z, fmaf(mv.w, w4.w, a[p]))));
        }
    }
    const float bias = bo[tid];
    #pragma unroll
    for (int p = 0; p < 16; ++p) {
        out[(size_t)(p0 + p) * CC + tid] = a[p] + bias;
    }
}

extern "C" void kernel_launch(void* const* d_in, const int* in_sizes, int n_in,
                              void* d_out, int out_size, void* d_ws, size_t ws_size,
                              hipStream_t stream)
{
    const float* x   = (const float*)d_in[0];
    const float* lnw = (const float*)d_in[1];
    const float* lnb = (const float*)d_in[2];
    const float* Wq  = (const float*)d_in[3];
    const float* Wk  = (const float*)d_in[4];
    const float* Wv  = (const float*)d_in[5];
    const float* Wo  = (const float*)d_in[6];
    const float* bo  = (const float*)d_in[7];

    char* wsb = (char*)d_ws;
    __hip_bfloat16* qb  = (__hip_bfloat16*)wsb;                    // 2,359,296 B
    __hip_bfloat16* kb  = qb + NPC;                                // 2,359,296 B
    __hip_bfloat16* vtb = kb + NPC;                                // 2,359,296 B
    float* O = (float*)(wsb + (size_t)3 * NPC * 2);                // 8,388,608 B

    k_ln_qkv<<<NPIX / 16, 256, 0, stream>>>(x, lnw, lnb, Wq, Wk, Wv, qb, kb, vtb);
    k_attn_mfma<<<4 * NHEADS * (SEQ / 32), 64, 0, stream>>>(qb, kb, vtb, O);
    k_merge_proj<<<NPIX / 16, 256, 0, stream>>>(O, Wo, bo, (float*)d_out);
}

// Round 4
// 159.424 us; speedup vs baseline: 4.0904x; 1.2966x over previous
//
#include <hip/hip_runtime.h>
#include <hip/hip_bf16.h>

#define TT 2
#define HH 48
#define WW 48
#define CC 256
#define NHEADS 8
#define HDIM 32
#define SEQ 2048
#define NPIX (TT*HH*WW)   /* 4608 */
#define NPC  (NPIX*CC)    /* 1179648 */
#define MFIX 12.0f        /* fixed softmax max (log2 domain) */

typedef __attribute__((ext_vector_type(8))) short bf16x8;
typedef __attribute__((ext_vector_type(4))) short bf16x4;
typedef __attribute__((ext_vector_type(4))) float f32x4;

__device__ inline unsigned cvt_pk_bf16(float lo, float hi) {
    unsigned r;
    asm("v_cvt_pk_bf16_f32 %0, %1, %2" : "=v"(r) : "v"(lo), "v"(hi));
    return r;
}
// D = A(16x16 bf16) * B(16x16 bf16) + D  -- K=16 MFMA via asm (ISA §10)
__device__ inline f32x4 mfma16(bf16x4 a, bf16x4 b, f32x4 c) {
    asm("v_mfma_f32_16x16x16_bf16 %0, %1, %2, %0" : "+v"(c) : "v"(a), "v"(b));
    return c;
}

// ---------------- Kernel 0: weights -> bf16 (QSC folded into Wq) -------------
__global__ __launch_bounds__(256) void k_prep(
    const float* __restrict__ Wq, const float* __restrict__ Wk,
    const float* __restrict__ Wv, const float* __restrict__ Wo,
    __hip_bfloat16* __restrict__ wb, __hip_bfloat16* __restrict__ wob)
{
    const float QSC = 0.17677669529663688f * 1.4426950408889634f;
    const int idx = blockIdx.x * 256 + threadIdx.x;  // 65536 float4 groups
    const int e = idx * 4;
    const int row = e >> 8;
    const float* src;
    float sc = 1.f;
    if (row < 256)      { src = Wq + e;          sc = QSC; }
    else if (row < 512) { src = Wk + (e - 65536); }
    else if (row < 768) { src = Wv + (e - 131072); }
    else                { src = Wo + (e - 196608); }
    const float4 t = *reinterpret_cast<const float4*>(src);
    uint2 st;
    st.x = cvt_pk_bf16(t.x * sc, t.y * sc);
    st.y = cvt_pk_bf16(t.z * sc, t.w * sc);
    if (row < 768) *reinterpret_cast<uint2*>(wb + e) = st;
    else           *reinterpret_cast<uint2*>(wob + (e - 196608)) = st;
}

// ---------------- Kernel 1: LayerNorm + one QKV projection (MFMA) ------------
// grid = 72 px-blocks x 3 matrices; block = 256 thr; 64 px/block.
// xn (bf16) staged in LDS [64][264] (padded). Per wave: 16-px tile, 16 oc-tiles.
// mat 0/1 (q,k): C[oc][px] = mfma(W, xn^T) -> row-major q/k, 8B stores.
// mat 2   (v):   C[px][oc] = mfma(xn, W^T) -> transposed vtb[ch][px], 8B stores.
__global__ __launch_bounds__(256) void k_ln_qkv2(
    const float* __restrict__ x,
    const float* __restrict__ lnw, const float* __restrict__ lnb,
    const __hip_bfloat16* __restrict__ wb,
    __hip_bfloat16* __restrict__ qb, __hip_bfloat16* __restrict__ kb,
    __hip_bfloat16* __restrict__ vtb)
{
    __shared__ __hip_bfloat16 xn[64][264];
    const int tid  = threadIdx.x;
    const int wv_  = tid >> 6;
    const int lane = tid & 63;
    const int mat  = blockIdx.x % 3;
    const int p0   = (blockIdx.x / 3) * 64;

    const float4 w4 = *reinterpret_cast<const float4*>(lnw + lane * 4);
    const float4 b4 = *reinterpret_cast<const float4*>(lnb + lane * 4);
    for (int i = 0; i < 16; ++i) {
        const int pl = wv_ * 16 + i;
        const float4 xv = *reinterpret_cast<const float4*>(x + (size_t)(p0 + pl) * CC + lane * 4);
        float s  = xv.x + xv.y + xv.z + xv.w;
        float s2 = xv.x*xv.x + xv.y*xv.y + xv.z*xv.z + xv.w*xv.w;
        #pragma unroll
        for (int m = 1; m < 64; m <<= 1) {
            s  += __shfl_xor(s,  m, 64);
            s2 += __shfl_xor(s2, m, 64);
        }
        const float mu   = s * (1.0f / CC);
        const float var  = s2 * (1.0f / CC) - mu * mu;
        const float rstd = rsqrtf(var + 1e-6f);
        uint2 st;
        st.x = cvt_pk_bf16((xv.x - mu) * rstd * w4.x + b4.x, (xv.y - mu) * rstd * w4.y + b4.y);
        st.y = cvt_pk_bf16((xv.z - mu) * rstd * w4.z + b4.z, (xv.w - mu) * rstd * w4.w + b4.w);
        *reinterpret_cast<uint2*>(&xn[pl][lane * 4]) = st;
    }
    __syncthreads();

    const int m16 = lane & 15, g = lane >> 4;
    bf16x8 xf[8];
    #pragma unroll
    for (int k = 0; k < 8; ++k)
        xf[k] = *reinterpret_cast<const bf16x8*>(&xn[wv_ * 16 + m16][k * 32 + g * 8]);

    const __hip_bfloat16* wbase = wb + (size_t)mat * 256 * CC;
    const int pxb = p0 + wv_ * 16;

    for (int oct = 0; oct < 16; ++oct) {
        const __hip_bfloat16* wrow = wbase + (size_t)(oct * 16 + m16) * CC;
        f32x4 c = {0.f, 0.f, 0.f, 0.f};
        if (mat < 2) {
            #pragma unroll
            for (int k = 0; k < 8; ++k) {
                const bf16x8 wf = *reinterpret_cast<const bf16x8*>(wrow + k * 32 + g * 8);
                c = __builtin_amdgcn_mfma_f32_16x16x32_bf16(wf, xf[k], c, 0, 0, 0);
            }
            uint2 st;
            st.x = cvt_pk_bf16(c[0], c[1]);
            st.y = cvt_pk_bf16(c[2], c[3]);
            __hip_bfloat16* dst = (mat == 0) ? qb : kb;
            *reinterpret_cast<uint2*>(dst + (size_t)(pxb + m16) * CC + oct * 16 + g * 4) = st;
        } else {
            #pragma unroll
            for (int k = 0; k < 8; ++k) {
                const bf16x8 wf = *reinterpret_cast<const bf16x8*>(wrow + k * 32 + g * 8);
                c = __builtin_amdgcn_mfma_f32_16x16x32_bf16(xf[k], wf, c, 0, 0, 0);
            }
            uint2 st;
            st.x = cvt_pk_bf16(c[0], c[1]);
            st.y = cvt_pk_bf16(c[2], c[3]);
            *reinterpret_cast<uint2*>(vtb + (size_t)(oct * 16 + m16) * NPIX + pxb + g * 4) = st;
        }
    }
}

// ---------------- Kernel 2: MFMA flash attention, fixed-max ------------------
// One wave per block; 32 q-rows of one (win, head). Swapped QK^T (16x16x32):
// score C row = key = 4g+r  ==  K=16 PV B-frag k index -> ZERO-permute PV via
// 2x v_mfma_f32_16x16x16_bf16 per (dt,kt). No LDS, no barriers, no rescale.
__global__ __launch_bounds__(64) void k_attn_mfma(
    const __hip_bfloat16* __restrict__ qbp, const __hip_bfloat16* __restrict__ kbp,
    const __hip_bfloat16* __restrict__ vtb, float* __restrict__ O)
{
    const int lane = threadIdx.x;
    const int bid  = blockIdx.x;
    const int qblk = bid & 63;
    const int head = (bid >> 6) & 7;
    const int win  = bid >> 9;
    const int rs = (win >> 1) * 16, cs = (win & 1) * 16;
    const int g = lane >> 4, q16 = lane & 15;

    bf16x8 qf[2];
    #pragma unroll
    for (int qt = 0; qt < 2; ++qt) {
        const int s = qblk * 32 + qt * 16 + q16;
        const int tt = s >> 10, yi = (s >> 5) & 31, xj = s & 31;
        const int qpix = (tt * HH + rs + yi) * WW + cs + xj;
        qf[qt] = *reinterpret_cast<const bf16x8*>(qbp + (size_t)qpix * CC + head * HDIM + g * 8);
    }

    f32x4 acc[2][2]; // [dt][qt]
    #pragma unroll
    for (int a = 0; a < 2; ++a)
        #pragma unroll
        for (int b = 0; b < 2; ++b) acc[a][b] = (f32x4){0.f, 0.f, 0.f, 0.f};
    float lsum[2] = {0.f, 0.f};

    const __hip_bfloat16* vrow0 = vtb + (size_t)(head * HDIM + q16) * NPIX;
    const __hip_bfloat16* vrow1 = vrow0 + (size_t)16 * NPIX;

    for (int kv0 = 0; kv0 < SEQ; kv0 += 32) {
        // K A-frags (16x16x32): lane holds K[key = kt*16 + q16][hd = g*8+j]
        bf16x8 kf0, kf1;
        {
            int sk = kv0 + q16;
            int tt = sk >> 10, yi = (sk >> 5) & 31, xj = sk & 31;
            int kpix = (tt * HH + rs + yi) * WW + cs + xj;
            kf0 = *reinterpret_cast<const bf16x8*>(kbp + (size_t)kpix * CC + head * HDIM + g * 8);
            sk = kv0 + 16 + q16;
            tt = sk >> 10; yi = (sk >> 5) & 31; xj = sk & 31;
            kpix = (tt * HH + rs + yi) * WW + cs + xj;
            kf1 = *reinterpret_cast<const bf16x8*>(kbp + (size_t)kpix * CC + head * HDIM + g * 8);
        }
        // V A-frags (16x16x16): lane holds V[key = ktblk + g*4 + j][d = dt*16 + q16]
        bf16x4 vf00, vf01, vf10, vf11; // [dt][kt]
        {
            int sk = kv0 + g * 4;
            int tt = sk >> 10, yi = (sk >> 5) & 31, xj = sk & 31;
            int vp = (tt * HH + rs + yi) * WW + cs + xj;
            vf00 = *reinterpret_cast<const bf16x4*>(vrow0 + vp);
            vf10 = *reinterpret_cast<const bf16x4*>(vrow1 + vp);
            sk = kv0 + 16 + g * 4;
            tt = sk >> 10; yi = (sk >> 5) & 31; xj = sk & 31;
            vp = (tt * HH + rs + yi) * WW + cs + xj;
            vf01 = *reinterpret_cast<const bf16x4*>(vrow0 + vp);
            vf11 = *reinterpret_cast<const bf16x4*>(vrow1 + vp);
        }
        #pragma unroll
        for (int qt = 0; qt < 2; ++qt) {
            const f32x4 z = {0.f, 0.f, 0.f, 0.f};
            const f32x4 s0 = __builtin_amdgcn_mfma_f32_16x16x32_bf16(kf0, qf[qt], z, 0, 0, 0);
            const f32x4 s1 = __builtin_amdgcn_mfma_f32_16x16x32_bf16(kf1, qf[qt], z, 0, 0, 0);
            const float p00 = exp2f(s0[0] - MFIX), p01 = exp2f(s0[1] - MFIX);
            const float p02 = exp2f(s0[2] - MFIX), p03 = exp2f(s0[3] - MFIX);
            const float p10 = exp2f(s1[0] - MFIX), p11 = exp2f(s1[1] - MFIX);
            const float p12 = exp2f(s1[2] - MFIX), p13 = exp2f(s1[3] - MFIX);
            lsum[qt] += ((p00 + p01) + (p02 + p03)) + ((p10 + p11) + (p12 + p13));
            union { unsigned u[2]; bf16x4 v; } pA, pB;
            pA.u[0] = cvt_pk_bf16(p00, p01); pA.u[1] = cvt_pk_bf16(p02, p03);
            pB.u[0] = cvt_pk_bf16(p10, p11); pB.u[1] = cvt_pk_bf16(p12, p13);
            acc[0][qt] = mfma16(vf00, pA.v, acc[0][qt]);
            acc[1][qt] = mfma16(vf10, pA.v, acc[1][qt]);
            acc[0][qt] = mfma16(vf01, pB.v, acc[0][qt]);
            acc[1][qt] = mfma16(vf11, pB.v, acc[1][qt]);
        }
    }

    #pragma unroll
    for (int qt = 0; qt < 2; ++qt) {
        float l = lsum[qt];
        l += __shfl_xor(l, 16, 64);
        l += __shfl_xor(l, 32, 64);
        const float inv = 1.0f / l;
        const int s = qblk * 32 + qt * 16 + q16;
        const int tt = s >> 10, yi = (s >> 5) & 31, xj = s & 31;
        const size_t opix = (size_t)(win * TT + tt) * 1024 + yi * 32 + xj;
        #pragma unroll
        for (int dt = 0; dt < 2; ++dt) {
            f32x4 o = acc[dt][qt];
            o *= inv;
            *reinterpret_cast<f32x4*>(O + opix * CC + head * HDIM + dt * 16 + g * 4) = o;
        }
    }
}

// ---------------- Kernel 3: overlap-add merge + output projection (MFMA) -----
__global__ __launch_bounds__(256) void k_merge_proj2(
    const float* __restrict__ O, const __hip_bfloat16* __restrict__ wob,
    const float* __restrict__ bo, float* __restrict__ out)
{
    __shared__ __hip_bfloat16 md[64][264];
    const int tid  = threadIdx.x;
    const int wv_  = tid >> 6;
    const int lane = tid & 63;
    const int p0   = blockIdx.x * 64;

    for (int i = 0; i < 16; ++i) {
        const int pl = wv_ * 16 + i;
        const int p  = p0 + pl;
        const int tt  = p / (HH * WW);
        const int rem = p % (HH * WW);
        const int y   = rem / WW;
        const int xc  = rem % WW;
        float4 a = make_float4(0.f, 0.f, 0.f, 0.f);
        int cnt = 0;
        for (int wr = 0; wr < 2; ++wr) {
            const int ii = y - wr * 16;
            if (ii < 0 || ii >= 32) continue;
            for (int wc = 0; wc < 2; ++wc) {
                const int jj = xc - wc * 16;
                if (jj < 0 || jj >= 32) continue;
                const int win = wr * 2 + wc;
                const size_t ob = ((size_t)((win * TT + tt) * 1024 + ii * 32 + jj)) * CC + lane * 4;
                const float4 t = *reinterpret_cast<const float4*>(O + ob);
                a.x += t.x; a.y += t.y; a.z += t.z; a.w += t.w;
                ++cnt;
            }
        }
        const float ic = 1.0f / (float)cnt;
        uint2 st;
        st.x = cvt_pk_bf16(a.x * ic, a.y * ic);
        st.y = cvt_pk_bf16(a.z * ic, a.w * ic);
        *reinterpret_cast<uint2*>(&md[pl][lane * 4]) = st;
    }
    __syncthreads();

    const int m16 = lane & 15, g = lane >> 4;
    bf16x8 xf[8];
    #pragma unroll
    for (int k = 0; k < 8; ++k)
        xf[k] = *reinterpret_cast<const bf16x8*>(&md[wv_ * 16 + m16][k * 32 + g * 8]);

    const int pxb = p0 + wv_ * 16;
    for (int oct = 0; oct < 16; ++oct) {
        const __hip_bfloat16* wrow = wob + (size_t)(oct * 16 + m16) * CC;
        f32x4 c = {0.f, 0.f, 0.f, 0.f};
        #pragma unroll
        for (int k = 0; k < 8; ++k) {
            const bf16x8 wf = *reinterpret_cast<const bf16x8*>(wrow + k * 32 + g * 8);
            c = __builtin_amdgcn_mfma_f32_16x16x32_bf16(wf, xf[k], c, 0, 0, 0);
        }
        const float4 b4 = *reinterpret_cast<const float4*>(bo + oct * 16 + g * 4);
        c[0] += b4.x; c[1] += b4.y; c[2] += b4.z; c[3] += b4.w;
        *reinterpret_cast<f32x4*>(out + (size_t)(pxb + m16) * CC + oct * 16 + g * 4) = c;
    }
}

extern "C" void kernel_launch(void* const* d_in, const int* in_sizes, int n_in,
                              void* d_out, int out_size, void* d_ws, size_t ws_size,
                              hipStream_t stream)
{
    const float* x   = (const float*)d_in[0];
    const float* lnw = (const float*)d_in[1];
    const float* lnb = (const float*)d_in[2];
    const float* Wq  = (const float*)d_in[3];
    const float* Wk  = (const float*)d_in[4];
    const float* Wv  = (const float*)d_in[5];
    const float* Wo  = (const float*)d_in[6];
    const float* bo  = (const float*)d_in[7];

    char* wsb = (char*)d_ws;
    __hip_bfloat16* qb  = (__hip_bfloat16*)wsb;                       // 2,359,296 B
    __hip_bfloat16* kb  = qb + NPC;                                   // 2,359,296 B
    __hip_bfloat16* vtb = kb + NPC;                                   // 2,359,296 B
    float* O = (float*)(wsb + (size_t)3 * NPC * 2);                   // 8,388,608 B
    __hip_bfloat16* wb  = (__hip_bfloat16*)(wsb + (size_t)3 * NPC * 2 + 8388608); // 393,216 B
    __hip_bfloat16* wob = wb + 768 * CC;                              // 131,072 B

    k_prep<<<256, 256, 0, stream>>>(Wq, Wk, Wv, Wo, wb, wob);
    k_ln_qkv2<<<216, 256, 0, stream>>>(x, lnw, lnb, wb, qb, kb, vtb);
    k_attn_mfma<<<4 * NHEADS * (SEQ / 32), 64, 0, stream>>>(qb, kb, vtb, O);
    k_merge_proj2<<<72, 256, 0, stream>>>(O, wob, bo, (float*)d_out);
}

// Round 5
// 144.207 us; speedup vs baseline: 4.5221x; 1.1055x over previous
//
#include <hip/hip_runtime.h>
#include <hip/hip_bf16.h>

#define TT 2
#define HH 48
#define WW 48
#define CC 256
#define NHEADS 8
#define HDIM 32
#define SEQ 2048
#define NPIX (TT*HH*WW)   /* 4608 */
#define NPC  (NPIX*CC)    /* 1179648 */
#define MFIX 12.0f        /* fixed softmax max (log2 domain) */
#define OSZ  (4*SEQ*CC)   /* 2097152 floats per split-O */
#define LSZ  (4*NHEADS*SEQ) /* 65536 floats per split-lsum */

typedef __attribute__((ext_vector_type(8))) short bf16x8;
typedef __attribute__((ext_vector_type(4))) short bf16x4;
typedef __attribute__((ext_vector_type(4))) float f32x4;

#if __has_builtin(__builtin_amdgcn_exp2f)
#define EXP2(x) __builtin_amdgcn_exp2f(x)
#else
#define EXP2(x) exp2f(x)
#endif
#if __has_builtin(__builtin_amdgcn_rcpf)
#define RCP(x) __builtin_amdgcn_rcpf(x)
#else
#define RCP(x) (1.0f/(x))
#endif

__device__ inline unsigned cvt_pk_bf16(float lo, float hi) {
    unsigned r;
    asm("v_cvt_pk_bf16_f32 %0, %1, %2" : "=v"(r) : "v"(lo), "v"(hi));
    return r;
}
__device__ inline f32x4 mfma16(bf16x4 a, bf16x4 b, f32x4 c) {
    asm("v_mfma_f32_16x16x16_bf16 %0, %1, %2, %0" : "+v"(c) : "v"(a), "v"(b));
    return c;
}

// ---------------- Kernel 0: weights -> bf16 (QSC folded into Wq) -------------
__global__ __launch_bounds__(256) void k_prep(
    const float* __restrict__ Wq, const float* __restrict__ Wk,
    const float* __restrict__ Wv, const float* __restrict__ Wo,
    __hip_bfloat16* __restrict__ wb, __hip_bfloat16* __restrict__ wob)
{
    const float QSC = 0.17677669529663688f * 1.4426950408889634f;
    const int idx = blockIdx.x * 256 + threadIdx.x;
    const int e = idx * 4;
    const int row = e >> 8;
    const float* src;
    float sc = 1.f;
    if (row < 256)      { src = Wq + e;          sc = QSC; }
    else if (row < 512) { src = Wk + (e - 65536); }
    else if (row < 768) { src = Wv + (e - 131072); }
    else                { src = Wo + (e - 196608); }
    const float4 t = *reinterpret_cast<const float4*>(src);
    uint2 st;
    st.x = cvt_pk_bf16(t.x * sc, t.y * sc);
    st.y = cvt_pk_bf16(t.z * sc, t.w * sc);
    if (row < 768) *reinterpret_cast<uint2*>(wb + e) = st;
    else           *reinterpret_cast<uint2*>(wob + (e - 196608)) = st;
}

// ---------------- Kernel 1: LayerNorm -> xn (bf16) ----------------
// One wave per pixel; 4 waves/block; grid 1152.
__global__ __launch_bounds__(256) void k_ln(
    const float* __restrict__ x,
    const float* __restrict__ lnw, const float* __restrict__ lnb,
    __hip_bfloat16* __restrict__ xnb)
{
    const int lane = threadIdx.x & 63;
    const int pix  = blockIdx.x * 4 + (threadIdx.x >> 6);
    const float4 xv = *reinterpret_cast<const float4*>(x + (size_t)pix * CC + lane * 4);
    float s  = xv.x + xv.y + xv.z + xv.w;
    float s2 = xv.x*xv.x + xv.y*xv.y + xv.z*xv.z + xv.w*xv.w;
    #pragma unroll
    for (int m = 1; m < 64; m <<= 1) {
        s  += __shfl_xor(s,  m, 64);
        s2 += __shfl_xor(s2, m, 64);
    }
    const float mu   = s * (1.0f / CC);
    const float var  = s2 * (1.0f / CC) - mu * mu;
    const float rstd = rsqrtf(var + 1e-6f);
    const float4 w4 = *reinterpret_cast<const float4*>(lnw + lane * 4);
    const float4 b4 = *reinterpret_cast<const float4*>(lnb + lane * 4);
    uint2 st;
    st.x = cvt_pk_bf16((xv.x - mu) * rstd * w4.x + b4.x, (xv.y - mu) * rstd * w4.y + b4.y);
    st.y = cvt_pk_bf16((xv.z - mu) * rstd * w4.z + b4.z, (xv.w - mu) * rstd * w4.w + b4.w);
    *reinterpret_cast<uint2*>(xnb + (size_t)pix * CC + lane * 4) = st;
}

// ---------------- Kernel 2: QKV projection (MFMA) ----------------
// grid = 3 mats x 72 px-blocks x 4 oc-groups = 864; block 256.
// Wave: 16 px x 64 oc. mat 0/1 -> row-major q/k; mat 2 -> transposed vtb.
__global__ __launch_bounds__(256) void k_qkv(
    const __hip_bfloat16* __restrict__ xnb, const __hip_bfloat16* __restrict__ wb,
    __hip_bfloat16* __restrict__ qb, __hip_bfloat16* __restrict__ kb,
    __hip_bfloat16* __restrict__ vtb)
{
    const int tid  = threadIdx.x;
    const int wv_  = tid >> 6;
    const int lane = tid & 63;
    const int bid  = blockIdx.x;
    const int mat  = bid / 288;
    const int r    = bid % 288;
    const int ocg  = r & 3;
    const int p0   = (r >> 2) * 64;
    const int m16 = lane & 15, g = lane >> 4;
    const int pxb = p0 + wv_ * 16;

    bf16x8 xf[8];
    #pragma unroll
    for (int k = 0; k < 8; ++k)
        xf[k] = *reinterpret_cast<const bf16x8*>(xnb + (size_t)(pxb + m16) * CC + k * 32 + g * 8);

    const __hip_bfloat16* wbase = wb + (size_t)mat * 256 * CC;
    #pragma unroll
    for (int oct = 0; oct < 4; ++oct) {
        const int ocb = ocg * 64 + oct * 16;
        const __hip_bfloat16* wrow = wbase + (size_t)(ocb + m16) * CC;
        f32x4 c = {0.f, 0.f, 0.f, 0.f};
        if (mat < 2) {
            #pragma unroll
            for (int k = 0; k < 8; ++k) {
                const bf16x8 wf = *reinterpret_cast<const bf16x8*>(wrow + k * 32 + g * 8);
                c = __builtin_amdgcn_mfma_f32_16x16x32_bf16(wf, xf[k], c, 0, 0, 0);
            }
            uint2 st;
            st.x = cvt_pk_bf16(c[0], c[1]);
            st.y = cvt_pk_bf16(c[2], c[3]);
            __hip_bfloat16* dst = (mat == 0) ? qb : kb;
            *reinterpret_cast<uint2*>(dst + (size_t)(pxb + m16) * CC + ocb + g * 4) = st;
        } else {
            #pragma unroll
            for (int k = 0; k < 8; ++k) {
                const bf16x8 wf = *reinterpret_cast<const bf16x8*>(wrow + k * 32 + g * 8);
                c = __builtin_amdgcn_mfma_f32_16x16x32_bf16(xf[k], wf, c, 0, 0, 0);
            }
            uint2 st;
            st.x = cvt_pk_bf16(c[0], c[1]);
            st.y = cvt_pk_bf16(c[2], c[3]);
            *reinterpret_cast<uint2*>(vtb + (size_t)(ocb + m16) * NPIX + pxb + g * 4) = st;
        }
    }
}

// ---------------- Kernel 3: MFMA flash attention, fixed-max, KV-split --------
// One wave per block; 32 q-rows of one (win, head, split). Within a split the
// t-plane is fixed and each 32-key tile is one window row -> all KV addresses
// are pure pointer bumps. Unnormalized acc -> O_part[split]; lsum separate.
__global__ __launch_bounds__(64) void k_attn_mfma(
    const __hip_bfloat16* __restrict__ qbp, const __hip_bfloat16* __restrict__ kbp,
    const __hip_bfloat16* __restrict__ vtb, float* __restrict__ Opart,
    float* __restrict__ lsb)
{
    const int lane = threadIdx.x;
    const int bid  = blockIdx.x;
    const int qblk = bid & 63;
    const int head = (bid >> 6) & 7;
    const int win  = (bid >> 9) & 3;
    const int split = bid >> 11;
    const int rs = (win >> 1) * 16, cs = (win & 1) * 16;
    const int g = lane >> 4, q16 = lane & 15;

    bf16x8 qf[2];
    #pragma unroll
    for (int qt = 0; qt < 2; ++qt) {
        const int s = qblk * 32 + qt * 16 + q16;
        const int tt = s >> 10, yi = (s >> 5) & 31, xj = s & 31;
        const int qpix = (tt * HH + rs + yi) * WW + cs + xj;
        qf[qt] = *reinterpret_cast<const bf16x8*>(qbp + (size_t)qpix * CC + head * HDIM + g * 8);
    }

    f32x4 acc[2][2]; // [dt][qt]
    #pragma unroll
    for (int a = 0; a < 2; ++a)
        #pragma unroll
        for (int b = 0; b < 2; ++b) acc[a][b] = (f32x4){0.f, 0.f, 0.f, 0.f};
    float lsum[2] = {0.f, 0.f};

    // key range [split*1024, split*1024+1024): t-plane = split, rows yi=0..31
    const int kpixrow = (split * HH + rs) * WW + cs;   // yi = 0 row base
    const __hip_bfloat16* kp0 = kbp + (size_t)(kpixrow + q16) * CC + head * HDIM + g * 8;
    const __hip_bfloat16* kp1 = kp0 + (size_t)16 * CC;
    const __hip_bfloat16* vp0 = vtb + (size_t)(head * HDIM + q16) * NPIX + kpixrow + g * 4;
    const __hip_bfloat16* vp1 = vp0 + (size_t)16 * NPIX;

    for (int it = 0; it < 32; ++it) {
        const bf16x8 kf0 = *reinterpret_cast<const bf16x8*>(kp0);
        const bf16x8 kf1 = *reinterpret_cast<const bf16x8*>(kp1);
        const bf16x4 vf00 = *reinterpret_cast<const bf16x4*>(vp0);
        const bf16x4 vf01 = *reinterpret_cast<const bf16x4*>(vp0 + 16);
        const bf16x4 vf10 = *reinterpret_cast<const bf16x4*>(vp1);
        const bf16x4 vf11 = *reinterpret_cast<const bf16x4*>(vp1 + 16);
        kp0 += (size_t)WW * CC; kp1 += (size_t)WW * CC;
        vp0 += WW; vp1 += WW;
        #pragma unroll
        for (int qt = 0; qt < 2; ++qt) {
            const f32x4 z = {0.f, 0.f, 0.f, 0.f};
            const f32x4 s0 = __builtin_amdgcn_mfma_f32_16x16x32_bf16(kf0, qf[qt], z, 0, 0, 0);
            const f32x4 s1 = __builtin_amdgcn_mfma_f32_16x16x32_bf16(kf1, qf[qt], z, 0, 0, 0);
            const float p00 = EXP2(s0[0] - MFIX), p01 = EXP2(s0[1] - MFIX);
            const float p02 = EXP2(s0[2] - MFIX), p03 = EXP2(s0[3] - MFIX);
            const float p10 = EXP2(s1[0] - MFIX), p11 = EXP2(s1[1] - MFIX);
            const float p12 = EXP2(s1[2] - MFIX), p13 = EXP2(s1[3] - MFIX);
            lsum[qt] += ((p00 + p01) + (p02 + p03)) + ((p10 + p11) + (p12 + p13));
            union { unsigned u[2]; bf16x4 v; } pA, pB;
            pA.u[0] = cvt_pk_bf16(p00, p01); pA.u[1] = cvt_pk_bf16(p02, p03);
            pB.u[0] = cvt_pk_bf16(p10, p11); pB.u[1] = cvt_pk_bf16(p12, p13);
            acc[0][qt] = mfma16(vf00, pA.v, acc[0][qt]);
            acc[1][qt] = mfma16(vf10, pA.v, acc[1][qt]);
            acc[0][qt] = mfma16(vf01, pB.v, acc[0][qt]);
            acc[1][qt] = mfma16(vf11, pB.v, acc[1][qt]);
        }
    }

    float* Op = Opart + (size_t)split * OSZ;
    float* lp = lsb + (size_t)split * LSZ + (size_t)(win * NHEADS + head) * SEQ;
    #pragma unroll
    for (int qt = 0; qt < 2; ++qt) {
        float l = lsum[qt];
        l += __shfl_xor(l, 16, 64);
        l += __shfl_xor(l, 32, 64);
        const int s = qblk * 32 + qt * 16 + q16;
        if (g == 0) lp[s] = l;
        const int tt = s >> 10, yi = (s >> 5) & 31, xj = s & 31;
        const size_t opix = (size_t)(win * TT + tt) * 1024 + yi * 32 + xj;
        #pragma unroll
        for (int dt = 0; dt < 2; ++dt) {
            *reinterpret_cast<f32x4*>(Op + opix * CC + head * HDIM + dt * 16 + g * 4) = acc[dt][qt];
        }
    }
}

// ---------------- Kernel 4: split-merge + normalize + overlap-add -> bf16 ----
// grid 288 x 256 thr; block = 16 pixels; wave handles 4 pixels; lane = 4 ch.
__global__ __launch_bounds__(256) void k_merge(
    const float* __restrict__ Opart, const float* __restrict__ lsb,
    __hip_bfloat16* __restrict__ mdb)
{
    const int tid  = threadIdx.x;
    const int wv_  = tid >> 6;
    const int lane = tid & 63;
    const int head = lane >> 3;        // channels lane*4..+3 are in this head
    const int p0   = blockIdx.x * 16;

    for (int i = 0; i < 4; ++i) {
        const int p  = p0 + wv_ * 4 + i;
        const int tt  = p / (HH * WW);
        const int rem = p % (HH * WW);
        const int y   = rem / WW;
        const int xc  = rem % WW;
        f32x4 a = {0.f, 0.f, 0.f, 0.f};
        int cnt = 0;
        for (int wr = 0; wr < 2; ++wr) {
            const int ii = y - wr * 16;
            if (ii < 0 || ii >= 32) continue;
            for (int wc = 0; wc < 2; ++wc) {
                const int jj = xc - wc * 16;
                if (jj < 0 || jj >= 32) continue;
                const int win = wr * 2 + wc;
                const int srow = tt * 1024 + ii * 32 + jj;
                const size_t ob = ((size_t)(win * TT + tt) * 1024 + ii * 32 + jj) * CC + lane * 4;
                const f32x4 t0 = *reinterpret_cast<const f32x4*>(Opart + ob);
                const f32x4 t1 = *reinterpret_cast<const f32x4*>(Opart + OSZ + ob);
                const size_t li = (size_t)(win * NHEADS + head) * SEQ + srow;
                const float l = lsb[li] + lsb[LSZ + li];
                a += (t0 + t1) * RCP(l);
                ++cnt;
            }
        }
        const float ic = (cnt == 1) ? 1.0f : ((cnt == 2) ? 0.5f : 0.25f);
        uint2 st;
        st.x = cvt_pk_bf16(a[0] * ic, a[1] * ic);
        st.y = cvt_pk_bf16(a[2] * ic, a[3] * ic);
        *reinterpret_cast<uint2*>(mdb + (size_t)p * CC + lane * 4) = st;
    }
}

// ---------------- Kernel 5: output projection (MFMA) + bias ------------------
// grid = 72 px-blocks x 4 oc-groups = 288; block 256; wave: 16 px x 64 oc.
__global__ __launch_bounds__(256) void k_proj(
    const __hip_bfloat16* __restrict__ mdb, const __hip_bfloat16* __restrict__ wob,
    const float* __restrict__ bo, float* __restrict__ out)
{
    const int tid  = threadIdx.x;
    const int wv_  = tid >> 6;
    const int lane = tid & 63;
    const int bid  = blockIdx.x;
    const int ocg  = bid & 3;
    const int p0   = (bid >> 2) * 64;
    const int m16 = lane & 15, g = lane >> 4;
    const int pxb = p0 + wv_ * 16;

    bf16x8 xf[8];
    #pragma unroll
    for (int k = 0; k < 8; ++k)
        xf[k] = *reinterpret_cast<const bf16x8*>(mdb + (size_t)(pxb + m16) * CC + k * 32 + g * 8);

    #pragma unroll
    for (int oct = 0; oct < 4; ++oct) {
        const int ocb = ocg * 64 + oct * 16;
        const __hip_bfloat16* wrow = wob + (size_t)(ocb + m16) * CC;
        f32x4 c = {0.f, 0.f, 0.f, 0.f};
        #pragma unroll
        for (int k = 0; k < 8; ++k) {
            const bf16x8 wf = *reinterpret_cast<const bf16x8*>(wrow + k * 32 + g * 8);
            c = __builtin_amdgcn_mfma_f32_16x16x32_bf16(wf, xf[k], c, 0, 0, 0);
        }
        const float4 b4 = *reinterpret_cast<const float4*>(bo + ocb + g * 4);
        c[0] += b4.x; c[1] += b4.y; c[2] += b4.z; c[3] += b4.w;
        *reinterpret_cast<f32x4*>(out + (size_t)(pxb + m16) * CC + ocb + g * 4) = c;
    }
}

extern "C" void kernel_launch(void* const* d_in, const int* in_sizes, int n_in,
                              void* d_out, int out_size, void* d_ws, size_t ws_size,
                              hipStream_t stream)
{
    const float* x   = (const float*)d_in[0];
    const float* lnw = (const float*)d_in[1];
    const float* lnb = (const float*)d_in[2];
    const float* Wq  = (const float*)d_in[3];
    const float* Wk  = (const float*)d_in[4];
    const float* Wv  = (const float*)d_in[5];
    const float* Wo  = (const float*)d_in[6];
    const float* bo  = (const float*)d_in[7];

    char* wsb = (char*)d_ws;
    __hip_bfloat16* qb  = (__hip_bfloat16*)wsb;                        // 2,359,296 B
    __hip_bfloat16* kb  = qb + NPC;                                    // 2,359,296 B
    __hip_bfloat16* vtb = kb + NPC;                                    // 2,359,296 B
    __hip_bfloat16* xnb = vtb + NPC;                                   // 2,359,296 B (reused as mdb)
    float* Opart = (float*)(wsb + (size_t)4 * NPC * 2);                // 2 x 8,388,608 B
    float* lsb   = Opart + (size_t)2 * OSZ;                            // 524,288 B
    __hip_bfloat16* wb  = (__hip_bfloat16*)(lsb + 2 * LSZ);            // 393,216 B
    __hip_bfloat16* wob = wb + 768 * CC;                               // 131,072 B

    k_prep<<<256, 256, 0, stream>>>(Wq, Wk, Wv, Wo, wb, wob);
    k_ln<<<NPIX / 4, 256, 0, stream>>>(x, lnw, lnb, xnb);
    k_qkv<<<864, 256, 0, stream>>>(xnb, wb, qb, kb, vtb);
    k_attn_mfma<<<4096, 64, 0, stream>>>(qb, kb, vtb, Opart, lsb);
    k_merge<<<288, 256, 0, stream>>>(Opart, lsb, xnb);
    k_proj<<<288, 256, 0, stream>>>(xnb, wob, bo, (float*)d_out);
}

// Round 6
// 103.543 us; speedup vs baseline: 6.2980x; 1.3927x over previous
//
#include <hip/hip_runtime.h>
#include <hip/hip_bf16.h>

#define TT 2
#define HH 48
#define WW 48
#define CC 256
#define NHEADS 8
#define HDIM 32
#define SEQ 2048
#define NPIX (TT*HH*WW)   /* 4608 */
#define NPC  (NPIX*CC)    /* 1179648 */
#define MFIX 12.0f        /* fixed softmax max (log2 domain) */
#define LSZ  (4*NHEADS*SEQ) /* 65536 floats per split-lsum */
#define OFS  (32*128*2*256) /* shorts per split of frag-ordered O = 2,097,152 */

typedef __attribute__((ext_vector_type(8))) short bf16x8;
typedef __attribute__((ext_vector_type(4))) short bf16x4;
typedef __attribute__((ext_vector_type(4))) float f32x4;

#if __has_builtin(__builtin_amdgcn_exp2f)
#define EXP2(x) __builtin_amdgcn_exp2f(x)
#else
#define EXP2(x) exp2f(x)
#endif
#if __has_builtin(__builtin_amdgcn_rcpf)
#define RCP(x) __builtin_amdgcn_rcpf(x)
#else
#define RCP(x) (1.0f/(x))
#endif

__device__ inline unsigned cvt_pk_bf16(float lo, float hi) {
    unsigned r;
    asm("v_cvt_pk_bf16_f32 %0, %1, %2" : "=v"(r) : "v"(lo), "v"(hi));
    return r;
}
__device__ inline f32x4 mfma16(bf16x4 a, bf16x4 b, f32x4 c) {
    asm("v_mfma_f32_16x16x16_bf16 %0, %1, %2, %0" : "+v"(c) : "v"(a), "v"(b));
    return c;
}
__device__ inline f32x4 b2f4(bf16x4 v) {
    union { bf16x4 b; unsigned short u[4]; } t; t.b = v;
    f32x4 r;
    #pragma unroll
    for (int i = 0; i < 4; ++i) { union { unsigned u; float f; } c; c.u = ((unsigned)t.u[i]) << 16; r[i] = c.f; }
    return r;
}

// ---------------- Kernel 0: weights -> bf16, FRAG-ORDERED ----------------
// Frag layout (A/B operand, 16x16x32): tile(oct: 16 oc-rows) x (k: 32-ch slab):
//   Wfp[((mat*16+oct)*8+k)*64 + g*16 + m16][j]  <- W[oct*16+m16][k*32+g*8+j]
__global__ __launch_bounds__(256) void k_prep(
    const float* __restrict__ Wq, const float* __restrict__ Wk,
    const float* __restrict__ Wv, const float* __restrict__ Wo,
    __hip_bfloat16* __restrict__ wfp, __hip_bfloat16* __restrict__ wofp)
{
    const float QSC = 0.17677669529663688f * 1.4426950408889634f;
    const int idx = blockIdx.x * 256 + threadIdx.x;  // 65536 float4 chunks
    const int e = idx * 4;
    const int grow = e >> 8;          // global row 0..1023
    const int c = e & 255;            // col of 4-chunk
    const float* src;
    float sc = 1.f;
    if (grow < 256)      { src = Wq + e;          sc = QSC; }
    else if (grow < 512) { src = Wk + (e - 65536); }
    else if (grow < 768) { src = Wv + (e - 131072); }
    else                 { src = Wo + (e - 196608); }
    const float4 t = *reinterpret_cast<const float4*>(src);
    uint2 st;
    st.x = cvt_pk_bf16(t.x * sc, t.y * sc);
    st.y = cvt_pk_bf16(t.z * sc, t.w * sc);
    const int r8  = grow & 255;
    const int oct = r8 >> 4, m16 = r8 & 15;
    const int k   = c >> 5, g = (c >> 3) & 3, j0 = c & 7;   // j0 in {0,4}
    if (grow < 768) {
        const int mat = grow >> 8;
        const size_t o = ((size_t)((mat * 16 + oct) * 8 + k) * 64 + g * 16 + m16) * 8 + j0;
        *reinterpret_cast<uint2*>(wfp + o) = st;
    } else {
        const size_t o = ((size_t)(oct * 8 + k) * 64 + g * 16 + m16) * 8 + j0;
        *reinterpret_cast<uint2*>(wofp + o) = st;
    }
}

// ---------------- Kernel 1: fused LayerNorm + QKV projection (MFMA) ----------
// grid = 3 mats x 72 px-blocks; block 256 (4 waves); 64 px/block.
// LN -> xn LDS (bf16), frag reads, W from frag-ordered wfp (contiguous loads).
__global__ __launch_bounds__(256) void k_lnqkv(
    const float* __restrict__ x,
    const float* __restrict__ lnw, const float* __restrict__ lnb,
    const __hip_bfloat16* __restrict__ wfp,
    __hip_bfloat16* __restrict__ qb, __hip_bfloat16* __restrict__ kb,
    __hip_bfloat16* __restrict__ vtb)
{
    __shared__ __hip_bfloat16 xn[64][264];
    const int tid  = threadIdx.x;
    const int wv_  = tid >> 6;
    const int lane = tid & 63;
    const int mat  = blockIdx.x / 72;
    const int p0   = (blockIdx.x % 72) * 64;

    const float4 w4 = *reinterpret_cast<const float4*>(lnw + lane * 4);
    const float4 b4 = *reinterpret_cast<const float4*>(lnb + lane * 4);
    for (int i = 0; i < 16; ++i) {
        const int pl = wv_ * 16 + i;
        const float4 xv = *reinterpret_cast<const float4*>(x + (size_t)(p0 + pl) * CC + lane * 4);
        float s  = xv.x + xv.y + xv.z + xv.w;
        float s2 = xv.x*xv.x + xv.y*xv.y + xv.z*xv.z + xv.w*xv.w;
        #pragma unroll
        for (int m = 1; m < 64; m <<= 1) {
            s  += __shfl_xor(s,  m, 64);
            s2 += __shfl_xor(s2, m, 64);
        }
        const float mu   = s * (1.0f / CC);
        const float var  = s2 * (1.0f / CC) - mu * mu;
        const float rstd = rsqrtf(var + 1e-6f);
        uint2 st;
        st.x = cvt_pk_bf16((xv.x - mu) * rstd * w4.x + b4.x, (xv.y - mu) * rstd * w4.y + b4.y);
        st.y = cvt_pk_bf16((xv.z - mu) * rstd * w4.z + b4.z, (xv.w - mu) * rstd * w4.w + b4.w);
        *reinterpret_cast<uint2*>(&xn[pl][lane * 4]) = st;
    }
    __syncthreads();

    const int m16 = lane & 15, g = lane >> 4;
    bf16x8 xf[8];
    #pragma unroll
    for (int k = 0; k < 8; ++k)
        xf[k] = *reinterpret_cast<const bf16x8*>(&xn[wv_ * 16 + m16][k * 32 + g * 8]);

    const int pxb = p0 + wv_ * 16;
    for (int oct = 0; oct < 16; ++oct) {
        const __hip_bfloat16* wt = wfp + ((size_t)(mat * 16 + oct) * 8) * 512;
        f32x4 c = {0.f, 0.f, 0.f, 0.f};
        if (mat < 2) {
            #pragma unroll
            for (int k = 0; k < 8; ++k) {
                const bf16x8 wf = *reinterpret_cast<const bf16x8*>(wt + (size_t)k * 512 + lane * 8);
                c = __builtin_amdgcn_mfma_f32_16x16x32_bf16(wf, xf[k], c, 0, 0, 0);
            }
            uint2 st;
            st.x = cvt_pk_bf16(c[0], c[1]);
            st.y = cvt_pk_bf16(c[2], c[3]);
            __hip_bfloat16* dst = (mat == 0) ? qb : kb;
            *reinterpret_cast<uint2*>(dst + (size_t)(pxb + m16) * CC + oct * 16 + g * 4) = st;
        } else {
            #pragma unroll
            for (int k = 0; k < 8; ++k) {
                const bf16x8 wf = *reinterpret_cast<const bf16x8*>(wt + (size_t)k * 512 + lane * 8);
                c = __builtin_amdgcn_mfma_f32_16x16x32_bf16(xf[k], wf, c, 0, 0, 0);
            }
            uint2 st;
            st.x = cvt_pk_bf16(c[0], c[1]);
            st.y = cvt_pk_bf16(c[2], c[3]);
            *reinterpret_cast<uint2*>(vtb + (size_t)(oct * 16 + m16) * NPIX + pxb + g * 4) = st;
        }
    }
}

// ---------------- Kernel 2: repack Q/K/V into per-(win,head) frag order ------
// Qfp/Kfp tile T (16 keys/queries): lane holds [row=q16][hd=g*8+j] -> lane*16B.
// Vfp tile (T,dt): lane holds V[key=T*16+4g+j][d=dt*16+q16] -> lane*8B.
__global__ __launch_bounds__(256) void k_repack(
    const __hip_bfloat16* __restrict__ qb, const __hip_bfloat16* __restrict__ kb,
    const __hip_bfloat16* __restrict__ vtb,
    __hip_bfloat16* __restrict__ Qfp, __hip_bfloat16* __restrict__ Kfp,
    __hip_bfloat16* __restrict__ Vfp)
{
    const int lane = threadIdx.x & 63;
    const int wid  = blockIdx.x * 4 + (threadIdx.x >> 6);  // 0..12287
    const int wh   = wid / 384;
    const int t    = wid % 384;
    const int win  = wh >> 3;
    const int head = wh & 7;
    const int rs = (win >> 1) * 16, cs = (win & 1) * 16;
    const int g = lane >> 4, q16 = lane & 15;

    if (t < 256) {
        const int T = t & 127;
        const int s = T * 16 + q16;
        const int tt = s >> 10, yi = (s >> 5) & 31, xj = s & 31;
        const int pix = (tt * HH + rs + yi) * WW + cs + xj;
        const __hip_bfloat16* src = ((t < 128) ? qb : kb) + (size_t)pix * CC + head * HDIM + g * 8;
        __hip_bfloat16* dst = ((t < 128) ? Qfp : Kfp) + ((size_t)(wh * 128 + T) * 64 + lane) * 8;
        *reinterpret_cast<bf16x8*>(dst) = *reinterpret_cast<const bf16x8*>(src);
    } else {
        const int T = t - 256;
        const int s0 = T * 16 + g * 4;
        const int tt = s0 >> 10, yi = (s0 >> 5) & 31, xj = s0 & 31;
        const int pix = (tt * HH + rs + yi) * WW + cs + xj;
        #pragma unroll
        for (int dt = 0; dt < 2; ++dt) {
            const __hip_bfloat16* src = vtb + (size_t)(head * HDIM + dt * 16 + q16) * NPIX + pix;
            __hip_bfloat16* dst = Vfp + (((size_t)(wh * 128 + T) * 2 + dt) * 64 + lane) * 4;
            *reinterpret_cast<bf16x4*>(dst) = *reinterpret_cast<const bf16x4*>(src);
        }
    }
}

// ---------------- Kernel 3: MFMA flash attention, frag-stream loads ----------
// One wave/block; 32 q-rows of one (win, head, split). All loads contiguous
// 16B/8B-per-lane streams with constant pointer bumps. Fixed-max softmax,
// zero-permute PV, unnormalized bf16 O-frags + lsum out.
__global__ __launch_bounds__(64) void k_attn(
    const __hip_bfloat16* __restrict__ Qfp, const __hip_bfloat16* __restrict__ Kfp,
    const __hip_bfloat16* __restrict__ Vfp, __hip_bfloat16* __restrict__ Ofp,
    float* __restrict__ lsb)
{
    const int lane = threadIdx.x;
    const int bid  = blockIdx.x;
    const int qblk = bid & 63;
    const int head = (bid >> 6) & 7;
    const int win  = (bid >> 9) & 3;
    const int split = bid >> 11;
    const int wh = win * 8 + head;
    const int g = lane >> 4, q16 = lane & 15;

    bf16x8 qf[2];
    qf[0] = *reinterpret_cast<const bf16x8*>(Qfp + ((size_t)(wh * 128 + qblk * 2) * 64 + lane) * 8);
    qf[1] = *reinterpret_cast<const bf16x8*>(Qfp + ((size_t)(wh * 128 + qblk * 2 + 1) * 64 + lane) * 8);

    f32x4 acc[2][2]; // [dt][qt]
    #pragma unroll
    for (int a = 0; a < 2; ++a)
        #pragma unroll
        for (int b = 0; b < 2; ++b) acc[a][b] = (f32x4){0.f, 0.f, 0.f, 0.f};
    float lsum[2] = {0.f, 0.f};

    const __hip_bfloat16* kp = Kfp + ((size_t)(wh * 128 + split * 64) * 64 + lane) * 8;
    const __hip_bfloat16* vp = Vfp + ((size_t)(wh * 128 + split * 64) * 2 * 64 + lane) * 4;

    for (int it = 0; it < 32; ++it) {
        const bf16x8 kf0 = *reinterpret_cast<const bf16x8*>(kp);
        const bf16x8 kf1 = *reinterpret_cast<const bf16x8*>(kp + 512);
        const bf16x4 vf00 = *reinterpret_cast<const bf16x4*>(vp);
        const bf16x4 vf10 = *reinterpret_cast<const bf16x4*>(vp + 256);
        const bf16x4 vf01 = *reinterpret_cast<const bf16x4*>(vp + 512);
        const bf16x4 vf11 = *reinterpret_cast<const bf16x4*>(vp + 768);
        kp += 1024; vp += 1024;
        #pragma unroll
        for (int qt = 0; qt < 2; ++qt) {
            const f32x4 z = {0.f, 0.f, 0.f, 0.f};
            const f32x4 s0 = __builtin_amdgcn_mfma_f32_16x16x32_bf16(kf0, qf[qt], z, 0, 0, 0);
            const f32x4 s1 = __builtin_amdgcn_mfma_f32_16x16x32_bf16(kf1, qf[qt], z, 0, 0, 0);
            const float p00 = EXP2(s0[0] - MFIX), p01 = EXP2(s0[1] - MFIX);
            const float p02 = EXP2(s0[2] - MFIX), p03 = EXP2(s0[3] - MFIX);
            const float p10 = EXP2(s1[0] - MFIX), p11 = EXP2(s1[1] - MFIX);
            const float p12 = EXP2(s1[2] - MFIX), p13 = EXP2(s1[3] - MFIX);
            lsum[qt] += ((p00 + p01) + (p02 + p03)) + ((p10 + p11) + (p12 + p13));
            union { unsigned u[2]; bf16x4 v; } pA, pB;
            pA.u[0] = cvt_pk_bf16(p00, p01); pA.u[1] = cvt_pk_bf16(p02, p03);
            pB.u[0] = cvt_pk_bf16(p10, p11); pB.u[1] = cvt_pk_bf16(p12, p13);
            acc[0][qt] = mfma16(vf00, pA.v, acc[0][qt]);
            acc[1][qt] = mfma16(vf10, pA.v, acc[1][qt]);
            acc[0][qt] = mfma16(vf01, pB.v, acc[0][qt]);
            acc[1][qt] = mfma16(vf11, pB.v, acc[1][qt]);
        }
    }

    float* lp = lsb + (size_t)split * LSZ + (size_t)wh * SEQ;
    #pragma unroll
    for (int qt = 0; qt < 2; ++qt) {
        float l = lsum[qt];
        l += __shfl_xor(l, 16, 64);
        l += __shfl_xor(l, 32, 64);
        const int s = qblk * 32 + qt * 16 + q16;
        if (g == 0) lp[s] = l;
        #pragma unroll
        for (int dt = 0; dt < 2; ++dt) {
            uint2 st;
            st.x = cvt_pk_bf16(acc[dt][qt][0], acc[dt][qt][1]);
            st.y = cvt_pk_bf16(acc[dt][qt][2], acc[dt][qt][3]);
            __hip_bfloat16* dst = Ofp + (size_t)split * OFS +
                (((size_t)(wh * 128 + qblk * 2 + qt) * 2 + dt) * 64 + lane) * 4;
            *reinterpret_cast<uint2*>(dst) = st;
        }
    }
}

// ---------------- Kernel 4: split-merge + overlap-add + projection -----------
// grid = 72 px-blocks x 4 oc-groups = 288; block 256.
__global__ __launch_bounds__(256) void k_merge_proj(
    const __hip_bfloat16* __restrict__ Ofp, const float* __restrict__ lsb,
    const __hip_bfloat16* __restrict__ wofp, const float* __restrict__ bo,
    float* __restrict__ out)
{
    __shared__ __hip_bfloat16 md[64][264];
    const int tid  = threadIdx.x;
    const int wv_  = tid >> 6;
    const int L    = tid & 63;
    const int ocg  = blockIdx.x & 3;
    const int p0   = (blockIdx.x >> 2) * 64;
    const int head = L >> 3, dt = (L >> 2) & 1, g4 = L & 3;

    for (int i = 0; i < 16; ++i) {
        const int pl = wv_ * 16 + i;
        const int p  = p0 + pl;
        const int tt  = p / (HH * WW);
        const int rem = p % (HH * WW);
        const int y   = rem / WW;
        const int xc  = rem % WW;
        f32x4 a = {0.f, 0.f, 0.f, 0.f};
        int cnt = 0;
        for (int wr = 0; wr < 2; ++wr) {
            const int ii = y - wr * 16;
            if (ii < 0 || ii >= 32) continue;
            for (int wc = 0; wc < 2; ++wc) {
                const int jj = xc - wc * 16;
                if (jj < 0 || jj >= 32) continue;
                const int win = wr * 2 + wc;
                const int srow = tt * 1024 + ii * 32 + jj;
                const size_t tb = (((size_t)((win * 8 + head) * 128 + (srow >> 4)) * 2 + dt) * 64
                                   + g4 * 16 + (srow & 15)) * 4;
                const bf16x4 t0 = *reinterpret_cast<const bf16x4*>(Ofp + tb);
                const bf16x4 t1 = *reinterpret_cast<const bf16x4*>(Ofp + OFS + tb);
                const size_t li = (size_t)(win * NHEADS + head) * SEQ + srow;
                const float l = lsb[li] + lsb[LSZ + li];
                a += (b2f4(t0) + b2f4(t1)) * RCP(l);
                ++cnt;
            }
        }
        const float ic = (cnt == 1) ? 1.0f : ((cnt == 2) ? 0.5f : 0.25f);
        uint2 st;
        st.x = cvt_pk_bf16(a[0] * ic, a[1] * ic);
        st.y = cvt_pk_bf16(a[2] * ic, a[3] * ic);
        *reinterpret_cast<uint2*>(&md[pl][L * 4]) = st;
    }
    __syncthreads();

    const int m16 = L & 15, g = L >> 4;
    bf16x8 xf[8];
    #pragma unroll
    for (int k = 0; k < 8; ++k)
        xf[k] = *reinterpret_cast<const bf16x8*>(&md[wv_ * 16 + m16][k * 32 + g * 8]);

    const int pxb = p0 + wv_ * 16;
    #pragma unroll
    for (int oct = 0; oct < 4; ++oct) {
        const int ocb = ocg * 64 + oct * 16;
        const __hip_bfloat16* wt = wofp + ((size_t)(ocg * 4 + oct) * 8) * 512;
        f32x4 c = {0.f, 0.f, 0.f, 0.f};
        #pragma unroll
        for (int k = 0; k < 8; ++k) {
            const bf16x8 wf = *reinterpret_cast<const bf16x8*>(wt + (size_t)k * 512 + L * 8);
            c = __builtin_amdgcn_mfma_f32_16x16x32_bf16(wf, xf[k], c, 0, 0, 0);
        }
        const float4 b4 = *reinterpret_cast<const float4*>(bo + ocb + g * 4);
        c[0] += b4.x; c[1] += b4.y; c[2] += b4.z; c[3] += b4.w;
        *reinterpret_cast<f32x4*>(out + (size_t)(pxb + m16) * CC + ocb + g * 4) = c;
    }
}

extern "C" void kernel_launch(void* const* d_in, const int* in_sizes, int n_in,
                              void* d_out, int out_size, void* d_ws, size_t ws_size,
                              hipStream_t stream)
{
    const float* x   = (const float*)d_in[0];
    const float* lnw = (const float*)d_in[1];
    const float* lnb = (const float*)d_in[2];
    const float* Wq  = (const float*)d_in[3];
    const float* Wk  = (const float*)d_in[4];
    const float* Wv  = (const float*)d_in[5];
    const float* Wo  = (const float*)d_in[6];
    const float* bo  = (const float*)d_in[7];

    // Region A (8,388,608 shorts = 16.8MB): qb/kb/vtb live until k_repack,
    // then the same region is overwritten as Ofp by k_attn (alias is safe:
    // strictly ordered same-stream kernels, fully rewritten every launch).
    __hip_bfloat16* regA = (__hip_bfloat16*)d_ws;
    __hip_bfloat16* qb   = regA;
    __hip_bfloat16* kb   = qb + NPC;
    __hip_bfloat16* vtb  = kb + NPC;
    __hip_bfloat16* Ofp  = regA;                   // 2*OFS = 4,194,304 shorts
    __hip_bfloat16* Qfp  = regA + 2 * OFS;         // 2,097,152 shorts each
    __hip_bfloat16* Kfp  = Qfp + 2097152;
    __hip_bfloat16* Vfp  = Kfp + 2097152;
    __hip_bfloat16* wfp  = Vfp + 2097152;          // 196,608 shorts
    __hip_bfloat16* wofp = wfp + 196608;           // 65,536 shorts
    float* lsb = (float*)(wofp + 65536);           // 2*LSZ floats

    k_prep<<<256, 256, 0, stream>>>(Wq, Wk, Wv, Wo, wfp, wofp);
    k_lnqkv<<<216, 256, 0, stream>>>(x, lnw, lnb, wfp, qb, kb, vtb);
    k_repack<<<3072, 256, 0, stream>>>(qb, kb, vtb, Qfp, Kfp, Vfp);
    k_attn<<<4096, 64, 0, stream>>>(Qfp, Kfp, Vfp, Ofp, lsb);
    k_merge_proj<<<288, 256, 0, stream>>>(Ofp, lsb, wofp, bo, (float*)d_out);
}

// Round 7
// 98.421 us; speedup vs baseline: 6.6257x; 1.0520x over previous
//
#include <hip/hip_runtime.h>
#include <hip/hip_bf16.h>

#define TT 2
#define HH 48
#define WW 48
#define CC 256
#define NHEADS 8
#define HDIM 32
#define SEQ 2048
#define NPIX (TT*HH*WW)   /* 4608 */
#define NPC  (NPIX*CC)    /* 1179648 */
#define MFIX 12.0f        /* fixed softmax max (log2 domain) */
#define LSZ  (4*NHEADS*SEQ) /* 65536 floats per split-lsum */
#define OFS  (32*128*2*256) /* shorts per split of frag-ordered O = 2,097,152 */

typedef __attribute__((ext_vector_type(8))) short bf16x8;
typedef __attribute__((ext_vector_type(4))) short bf16x4;
typedef __attribute__((ext_vector_type(4))) float f32x4;

#if __has_builtin(__builtin_amdgcn_exp2f)
#define EXP2(x) __builtin_amdgcn_exp2f(x)
#else
#define EXP2(x) exp2f(x)
#endif
#if __has_builtin(__builtin_amdgcn_rcpf)
#define RCP(x) __builtin_amdgcn_rcpf(x)
#else
#define RCP(x) (1.0f/(x))
#endif

__device__ inline unsigned cvt_pk_bf16(float lo, float hi) {
    unsigned r;
    asm("v_cvt_pk_bf16_f32 %0, %1, %2" : "=v"(r) : "v"(lo), "v"(hi));
    return r;
}
__device__ inline f32x4 mfma16(bf16x4 a, bf16x4 b, f32x4 c) {
    asm("v_mfma_f32_16x16x16_bf16 %0, %1, %2, %0" : "+v"(c) : "v"(a), "v"(b));
    return c;
}
__device__ inline f32x4 b2f4(bf16x4 v) {
    union { bf16x4 b; unsigned short u[4]; } t; t.b = v;
    f32x4 r;
    #pragma unroll
    for (int i = 0; i < 4; ++i) { union { unsigned u; float f; } c; c.u = ((unsigned)t.u[i]) << 16; r[i] = c.f; }
    return r;
}

// ---------------- Kernel 0: weights -> bf16, FRAG-ORDERED ----------------
__global__ __launch_bounds__(256) void k_prep(
    const float* __restrict__ Wq, const float* __restrict__ Wk,
    const float* __restrict__ Wv, const float* __restrict__ Wo,
    __hip_bfloat16* __restrict__ wfp, __hip_bfloat16* __restrict__ wofp)
{
    const float QSC = 0.17677669529663688f * 1.4426950408889634f;
    const int idx = blockIdx.x * 256 + threadIdx.x;  // 65536 float4 chunks
    const int e = idx * 4;
    const int grow = e >> 8;          // global row 0..1023
    const int c = e & 255;            // col of 4-chunk
    const float* src;
    float sc = 1.f;
    if (grow < 256)      { src = Wq + e;          sc = QSC; }
    else if (grow < 512) { src = Wk + (e - 65536); }
    else if (grow < 768) { src = Wv + (e - 131072); }
    else                 { src = Wo + (e - 196608); }
    const float4 t = *reinterpret_cast<const float4*>(src);
    uint2 st;
    st.x = cvt_pk_bf16(t.x * sc, t.y * sc);
    st.y = cvt_pk_bf16(t.z * sc, t.w * sc);
    const int r8  = grow & 255;
    const int oct = r8 >> 4, m16 = r8 & 15;
    const int k   = c >> 5, g = (c >> 3) & 3, j0 = c & 7;   // j0 in {0,4}
    if (grow < 768) {
        const int mat = grow >> 8;
        const size_t o = ((size_t)((mat * 16 + oct) * 8 + k) * 64 + g * 16 + m16) * 8 + j0;
        *reinterpret_cast<uint2*>(wfp + o) = st;
    } else {
        const size_t o = ((size_t)(oct * 8 + k) * 64 + g * 16 + m16) * 8 + j0;
        *reinterpret_cast<uint2*>(wofp + o) = st;
    }
}

// ---------------- Kernel 1: fused LayerNorm + QKV projection (MFMA) ----------
// grid = 3 mats x 72 px-blocks x 2 oc-groups = 432; block 256 (4 waves).
__global__ __launch_bounds__(256) void k_lnqkv(
    const float* __restrict__ x,
    const float* __restrict__ lnw, const float* __restrict__ lnb,
    const __hip_bfloat16* __restrict__ wfp,
    __hip_bfloat16* __restrict__ qb, __hip_bfloat16* __restrict__ kb,
    __hip_bfloat16* __restrict__ vtb)
{
    __shared__ __hip_bfloat16 xn[64][264];
    const int tid  = threadIdx.x;
    const int wv_  = tid >> 6;
    const int lane = tid & 63;
    const int mat  = blockIdx.x / 144;
    const int r    = blockIdx.x % 144;
    const int p0   = (r >> 1) * 64;
    const int ocg  = r & 1;

    const float4 w4 = *reinterpret_cast<const float4*>(lnw + lane * 4);
    const float4 b4 = *reinterpret_cast<const float4*>(lnb + lane * 4);
    for (int i = 0; i < 16; ++i) {
        const int pl = wv_ * 16 + i;
        const float4 xv = *reinterpret_cast<const float4*>(x + (size_t)(p0 + pl) * CC + lane * 4);
        float s  = xv.x + xv.y + xv.z + xv.w;
        float s2 = xv.x*xv.x + xv.y*xv.y + xv.z*xv.z + xv.w*xv.w;
        #pragma unroll
        for (int m = 1; m < 64; m <<= 1) {
            s  += __shfl_xor(s,  m, 64);
            s2 += __shfl_xor(s2, m, 64);
        }
        const float mu   = s * (1.0f / CC);
        const float var  = s2 * (1.0f / CC) - mu * mu;
        const float rstd = rsqrtf(var + 1e-6f);
        uint2 st;
        st.x = cvt_pk_bf16((xv.x - mu) * rstd * w4.x + b4.x, (xv.y - mu) * rstd * w4.y + b4.y);
        st.y = cvt_pk_bf16((xv.z - mu) * rstd * w4.z + b4.z, (xv.w - mu) * rstd * w4.w + b4.w);
        *reinterpret_cast<uint2*>(&xn[pl][lane * 4]) = st;
    }
    __syncthreads();

    const int m16 = lane & 15, g = lane >> 4;
    bf16x8 xf[8];
    #pragma unroll
    for (int k = 0; k < 8; ++k)
        xf[k] = *reinterpret_cast<const bf16x8*>(&xn[wv_ * 16 + m16][k * 32 + g * 8]);

    const int pxb = p0 + wv_ * 16;
    for (int o8 = 0; o8 < 8; ++o8) {
        const int oct = ocg * 8 + o8;
        const __hip_bfloat16* wt = wfp + ((size_t)(mat * 16 + oct) * 8) * 512;
        f32x4 c = {0.f, 0.f, 0.f, 0.f};
        if (mat < 2) {
            #pragma unroll
            for (int k = 0; k < 8; ++k) {
                const bf16x8 wf = *reinterpret_cast<const bf16x8*>(wt + (size_t)k * 512 + lane * 8);
                c = __builtin_amdgcn_mfma_f32_16x16x32_bf16(wf, xf[k], c, 0, 0, 0);
            }
            uint2 st;
            st.x = cvt_pk_bf16(c[0], c[1]);
            st.y = cvt_pk_bf16(c[2], c[3]);
            __hip_bfloat16* dst = (mat == 0) ? qb : kb;
            *reinterpret_cast<uint2*>(dst + (size_t)(pxb + m16) * CC + oct * 16 + g * 4) = st;
        } else {
            #pragma unroll
            for (int k = 0; k < 8; ++k) {
                const bf16x8 wf = *reinterpret_cast<const bf16x8*>(wt + (size_t)k * 512 + lane * 8);
                c = __builtin_amdgcn_mfma_f32_16x16x32_bf16(xf[k], wf, c, 0, 0, 0);
            }
            uint2 st;
            st.x = cvt_pk_bf16(c[0], c[1]);
            st.y = cvt_pk_bf16(c[2], c[3]);
            *reinterpret_cast<uint2*>(vtb + (size_t)(oct * 16 + m16) * NPIX + pxb + g * 4) = st;
        }
    }
}

// ---------------- Kernel 2: repack Q/K/V into per-(win,head) frag order ------
__global__ __launch_bounds__(256) void k_repack(
    const __hip_bfloat16* __restrict__ qb, const __hip_bfloat16* __restrict__ kb,
    const __hip_bfloat16* __restrict__ vtb,
    __hip_bfloat16* __restrict__ Qfp, __hip_bfloat16* __restrict__ Kfp,
    __hip_bfloat16* __restrict__ Vfp)
{
    const int lane = threadIdx.x & 63;
    const int wid  = blockIdx.x * 4 + (threadIdx.x >> 6);  // 0..12287
    const int wh   = wid / 384;
    const int t    = wid % 384;
    const int win  = wh >> 3;
    const int head = wh & 7;
    const int rs = (win >> 1) * 16, cs = (win & 1) * 16;
    const int g = lane >> 4, q16 = lane & 15;

    if (t < 256) {
        const int T = t & 127;
        const int s = T * 16 + q16;
        const int tt = s >> 10, yi = (s >> 5) & 31, xj = s & 31;
        const int pix = (tt * HH + rs + yi) * WW + cs + xj;
        const __hip_bfloat16* src = ((t < 128) ? qb : kb) + (size_t)pix * CC + head * HDIM + g * 8;
        __hip_bfloat16* dst = ((t < 128) ? Qfp : Kfp) + ((size_t)(wh * 128 + T) * 64 + lane) * 8;
        *reinterpret_cast<bf16x8*>(dst) = *reinterpret_cast<const bf16x8*>(src);
    } else {
        const int T = t - 256;
        const int s0 = T * 16 + g * 4;
        const int tt = s0 >> 10, yi = (s0 >> 5) & 31, xj = s0 & 31;
        const int pix = (tt * HH + rs + yi) * WW + cs + xj;
        #pragma unroll
        for (int dt = 0; dt < 2; ++dt) {
            const __hip_bfloat16* src = vtb + (size_t)(head * HDIM + dt * 16 + q16) * NPIX + pix;
            __hip_bfloat16* dst = Vfp + (((size_t)(wh * 128 + T) * 2 + dt) * 64 + lane) * 4;
            *reinterpret_cast<bf16x4*>(dst) = *reinterpret_cast<const bf16x4*>(src);
        }
    }
}

// ---------------- Kernel 3: MFMA flash attention, XCD-local K/V --------------
// 256-thr blocks (4 waves, 4 consecutive qblks); grid 1024.
// bid = qb4*64 + grp  ->  xcd(bid)=bid&7=grp&7: all 64 q-blocks of one
// (win,head,split) group land on ONE XCD; its K/V slab (128KB) stays L2-local.
__global__ __launch_bounds__(256) void k_attn(
    const __hip_bfloat16* __restrict__ Qfp, const __hip_bfloat16* __restrict__ Kfp,
    const __hip_bfloat16* __restrict__ Vfp, __hip_bfloat16* __restrict__ Ofp,
    float* __restrict__ lsb)
{
    const int lane = threadIdx.x & 63;
    const int wsub = threadIdx.x >> 6;
    const int bid  = blockIdx.x;
    const int grp  = bid & 63;          // (split,win,head) group -> fixed XCD
    const int qb4  = bid >> 6;          // 0..15
    const int qblk = qb4 * 4 + wsub;
    const int head = grp & 7;
    const int win  = (grp >> 3) & 3;
    const int split = grp >> 5;
    const int wh = win * 8 + head;
    const int g = lane >> 4, q16 = lane & 15;

    bf16x8 qf[2];
    qf[0] = *reinterpret_cast<const bf16x8*>(Qfp + ((size_t)(wh * 128 + qblk * 2) * 64 + lane) * 8);
    qf[1] = *reinterpret_cast<const bf16x8*>(Qfp + ((size_t)(wh * 128 + qblk * 2 + 1) * 64 + lane) * 8);

    f32x4 acc[2][2]; // [dt][qt]
    #pragma unroll
    for (int a = 0; a < 2; ++a)
        #pragma unroll
        for (int b = 0; b < 2; ++b) acc[a][b] = (f32x4){0.f, 0.f, 0.f, 0.f};
    float lsum[2] = {0.f, 0.f};

    const __hip_bfloat16* kp = Kfp + ((size_t)(wh * 128 + split * 64) * 64 + lane) * 8;
    const __hip_bfloat16* vp = Vfp + ((size_t)(wh * 128 + split * 64) * 2 * 64 + lane) * 4;

    for (int it = 0; it < 32; ++it) {
        const bf16x8 kf0 = *reinterpret_cast<const bf16x8*>(kp);
        const bf16x8 kf1 = *reinterpret_cast<const bf16x8*>(kp + 512);
        const bf16x4 vf00 = *reinterpret_cast<const bf16x4*>(vp);
        const bf16x4 vf10 = *reinterpret_cast<const bf16x4*>(vp + 256);
        const bf16x4 vf01 = *reinterpret_cast<const bf16x4*>(vp + 512);
        const bf16x4 vf11 = *reinterpret_cast<const bf16x4*>(vp + 768);
        kp += 1024; vp += 1024;
        #pragma unroll
        for (int qt = 0; qt < 2; ++qt) {
            const f32x4 z = {0.f, 0.f, 0.f, 0.f};
            const f32x4 s0 = __builtin_amdgcn_mfma_f32_16x16x32_bf16(kf0, qf[qt], z, 0, 0, 0);
            const f32x4 s1 = __builtin_amdgcn_mfma_f32_16x16x32_bf16(kf1, qf[qt], z, 0, 0, 0);
            const float p00 = EXP2(s0[0] - MFIX), p01 = EXP2(s0[1] - MFIX);
            const float p02 = EXP2(s0[2] - MFIX), p03 = EXP2(s0[3] - MFIX);
            const float p10 = EXP2(s1[0] - MFIX), p11 = EXP2(s1[1] - MFIX);
            const float p12 = EXP2(s1[2] - MFIX), p13 = EXP2(s1[3] - MFIX);
            lsum[qt] += ((p00 + p01) + (p02 + p03)) + ((p10 + p11) + (p12 + p13));
            union { unsigned u[2]; bf16x4 v; } pA, pB;
            pA.u[0] = cvt_pk_bf16(p00, p01); pA.u[1] = cvt_pk_bf16(p02, p03);
            pB.u[0] = cvt_pk_bf16(p10, p11); pB.u[1] = cvt_pk_bf16(p12, p13);
            acc[0][qt] = mfma16(vf00, pA.v, acc[0][qt]);
            acc[1][qt] = mfma16(vf10, pA.v, acc[1][qt]);
            acc[0][qt] = mfma16(vf01, pB.v, acc[0][qt]);
            acc[1][qt] = mfma16(vf11, pB.v, acc[1][qt]);
        }
    }

    float* lp = lsb + (size_t)split * LSZ + (size_t)wh * SEQ;
    #pragma unroll
    for (int qt = 0; qt < 2; ++qt) {
        float l = lsum[qt];
        l += __shfl_xor(l, 16, 64);
        l += __shfl_xor(l, 32, 64);
        const int s = qblk * 32 + qt * 16 + q16;
        if (g == 0) lp[s] = l;
        #pragma unroll
        for (int dt = 0; dt < 2; ++dt) {
            uint2 st;
            st.x = cvt_pk_bf16(acc[dt][qt][0], acc[dt][qt][1]);
            st.y = cvt_pk_bf16(acc[dt][qt][2], acc[dt][qt][3]);
            __hip_bfloat16* dst = Ofp + (size_t)split * OFS +
                (((size_t)(wh * 128 + qblk * 2 + qt) * 2 + dt) * 64 + lane) * 4;
            *reinterpret_cast<uint2*>(dst) = st;
        }
    }
}

// ---------------- Kernel 4: split-merge + overlap-add + projection -----------
__global__ __launch_bounds__(256) void k_merge_proj(
    const __hip_bfloat16* __restrict__ Ofp, const float* __restrict__ lsb,
    const __hip_bfloat16* __restrict__ wofp, const float* __restrict__ bo,
    float* __restrict__ out)
{
    __shared__ __hip_bfloat16 md[64][264];
    const int tid  = threadIdx.x;
    const int wv_  = tid >> 6;
    const int L    = tid & 63;
    const int ocg  = blockIdx.x & 3;
    const int p0   = (blockIdx.x >> 2) * 64;
    const int head = L >> 3, dt = (L >> 2) & 1, g4 = L & 3;

    for (int i = 0; i < 16; ++i) {
        const int pl = wv_ * 16 + i;
        const int p  = p0 + pl;
        const int tt  = p / (HH * WW);
        const int rem = p % (HH * WW);
        const int y   = rem / WW;
        const int xc  = rem % WW;
        f32x4 a = {0.f, 0.f, 0.f, 0.f};
        int cnt = 0;
        for (int wr = 0; wr < 2; ++wr) {
            const int ii = y - wr * 16;
            if (ii < 0 || ii >= 32) continue;
            for (int wc = 0; wc < 2; ++wc) {
                const int jj = xc - wc * 16;
                if (jj < 0 || jj >= 32) continue;
                const int win = wr * 2 + wc;
                const int srow = tt * 1024 + ii * 32 + jj;
                const size_t tb = (((size_t)((win * 8 + head) * 128 + (srow >> 4)) * 2 + dt) * 64
                                   + g4 * 16 + (srow & 15)) * 4;
                const bf16x4 t0 = *reinterpret_cast<const bf16x4*>(Ofp + tb);
                const bf16x4 t1 = *reinterpret_cast<const bf16x4*>(Ofp + OFS + tb);
                const size_t li = (size_t)(win * NHEADS + head) * SEQ + srow;
                const float l = lsb[li] + lsb[LSZ + li];
                a += (b2f4(t0) + b2f4(t1)) * RCP(l);
                ++cnt;
            }
        }
        const float ic = (cnt == 1) ? 1.0f : ((cnt == 2) ? 0.5f : 0.25f);
        uint2 st;
        st.x = cvt_pk_bf16(a[0] * ic, a[1] * ic);
        st.y = cvt_pk_bf16(a[2] * ic, a[3] * ic);
        *reinterpret_cast<uint2*>(&md[pl][L * 4]) = st;
    }
    __syncthreads();

    const int m16 = L & 15, g = L >> 4;
    bf16x8 xf[8];
    #pragma unroll
    for (int k = 0; k < 8; ++k)
        xf[k] = *reinterpret_cast<const bf16x8*>(&md[wv_ * 16 + m16][k * 32 + g * 8]);

    const int pxb = p0 + wv_ * 16;
    #pragma unroll
    for (int oct = 0; oct < 4; ++oct) {
        const int ocb = ocg * 64 + oct * 16;
        const __hip_bfloat16* wt = wofp + ((size_t)(ocg * 4 + oct) * 8) * 512;
        f32x4 c = {0.f, 0.f, 0.f, 0.f};
        #pragma unroll
        for (int k = 0; k < 8; ++k) {
            const bf16x8 wf = *reinterpret_cast<const bf16x8*>(wt + (size_t)k * 512 + L * 8);
            c = __builtin_amdgcn_mfma_f32_16x16x32_bf16(wf, xf[k], c, 0, 0, 0);
        }
        const float4 b4 = *reinterpret_cast<const float4*>(bo + ocb + g * 4);
        c[0] += b4.x; c[1] += b4.y; c[2] += b4.z; c[3] += b4.w;
        *reinterpret_cast<f32x4*>(out + (size_t)(pxb + m16) * CC + ocb + g * 4) = c;
    }
}

extern "C" void kernel_launch(void* const* d_in, const int* in_sizes, int n_in,
                              void* d_out, int out_size, void* d_ws, size_t ws_size,
                              hipStream_t stream)
{
    const float* x   = (const float*)d_in[0];
    const float* lnw = (const float*)d_in[1];
    const float* lnb = (const float*)d_in[2];
    const float* Wq  = (const float*)d_in[3];
    const float* Wk  = (const float*)d_in[4];
    const float* Wv  = (const float*)d_in[5];
    const float* Wo  = (const float*)d_in[6];
    const float* bo  = (const float*)d_in[7];

    // Region A: qb/kb/vtb live until k_repack, then overwritten as Ofp by
    // k_attn (safe: strictly ordered same-stream kernels, fully rewritten).
    __hip_bfloat16* regA = (__hip_bfloat16*)d_ws;
    __hip_bfloat16* qb   = regA;
    __hip_bfloat16* kb   = qb + NPC;
    __hip_bfloat16* vtb  = kb + NPC;
    __hip_bfloat16* Ofp  = regA;                   // 2*OFS shorts
    __hip_bfloat16* Qfp  = regA + 2 * OFS;
    __hip_bfloat16* Kfp  = Qfp + 2097152;
    __hip_bfloat16* Vfp  = Kfp + 2097152;
    __hip_bfloat16* wfp  = Vfp + 2097152;
    __hip_bfloat16* wofp = wfp + 196608;
    float* lsb = (float*)(wofp + 65536);

    k_prep<<<256, 256, 0, stream>>>(Wq, Wk, Wv, Wo, wfp, wofp);
    k_lnqkv<<<432, 256, 0, stream>>>(x, lnw, lnb, wfp, qb, kb, vtb);
    k_repack<<<3072, 256, 0, stream>>>(qb, kb, vtb, Qfp, Kfp, Vfp);
    k_attn<<<1024, 256, 0, stream>>>(Qfp, Kfp, Vfp, Ofp, lsb);
    k_merge_proj<<<288, 256, 0, stream>>>(Ofp, lsb, wofp, bo, (float*)d_out);
}